// Round 1
// baseline (4079.132 us; speedup 1.0000x reference)
//
#include <hip/hip_runtime.h>
#include <hip/hip_bf16.h>
#include <stdint.h>

#define DIM 2048
#define TSEQ 2048
#define BATCH 2
#define NH 32
#define NKV 4
#define HD 64
#define MROWS (BATCH*TSEQ)   // 4096
#define NQKV 2560            // 2048 q + 256 k + 256 v

typedef __attribute__((ext_vector_type(4))) float f32x4;
typedef __attribute__((ext_vector_type(8))) short bf16x8;
typedef unsigned short ushort_t;

__device__ __forceinline__ float bflo2f(unsigned int w) {
  union { unsigned int i; float f; } c; c.i = w << 16; return c.f;
}
__device__ __forceinline__ float bfhi2f(unsigned int w) {
  union { unsigned int i; float f; } c; c.i = w & 0xffff0000u; return c.f;
}
__device__ __forceinline__ unsigned short f2bf(float f) {
  union { float f; unsigned int i; } c; c.f = f;
  unsigned int x = c.i;
  x += 0x7fffu + ((x >> 16) & 1u);   // round to nearest even
  return (unsigned short)(x >> 16);
}

// ---------------- cast x (f32 -> bf16), 4 elems/thread ----------------
__global__ void cast_bf16_k(const float* __restrict__ in, ushort_t* __restrict__ out, int n4) {
  const int i = blockIdx.x * 256 + threadIdx.x;
  if (i >= n4) return;
  const float4 v = ((const float4*)in)[i];
  uint2 p;
  p.x = (unsigned int)f2bf(v.x) | ((unsigned int)f2bf(v.y) << 16);
  p.y = (unsigned int)f2bf(v.z) | ((unsigned int)f2bf(v.w) << 16);
  ((uint2*)out)[i] = p;
}

// ---------------- transpose-cast: w[K][N] f32 -> wt[N][K] bf16 ----------------
__global__ void transpose_cast(const float* __restrict__ w, ushort_t* __restrict__ wt, int K, int N) {
  __shared__ float tile[32][33];
  const int bk = blockIdx.x * 32;
  const int bn = blockIdx.y * 32;
  const int tx = threadIdx.x & 31;
  const int ty = threadIdx.x >> 5;  // 0..7
#pragma unroll
  for (int p = 0; p < 4; p++) {
    const int r = ty + p * 8;
    tile[r][tx] = w[(long)(bk + r) * N + bn + tx];
  }
  __syncthreads();
#pragma unroll
  for (int p = 0; p < 4; p++) {
    const int r = ty + p * 8;
    wt[(long)(bn + r) * K + bk + tx] = f2bf(tile[tx][r]);
  }
}

// ---------------- bf16 MFMA GEMM: C[M][N] = A[M][K] * BT[N][K]^T ----------------
// EPI 0: scatter to Q [B,T,H*D] bf16, K [B,Hkv,T,D] bf16, V^T [B,Hkv,D,T] bf16
// EPI 1: plain f32 C
template<int EPI>
__global__ __launch_bounds__(256, 2) void gemm_bt(
    const ushort_t* __restrict__ A, const ushort_t* __restrict__ BT,
    int M, int N, int K,
    float* __restrict__ Cf, ushort_t* __restrict__ Cq,
    ushort_t* __restrict__ Ck, ushort_t* __restrict__ Cv)
{
  __shared__ __align__(16) ushort_t As[128][72];
  __shared__ __align__(16) ushort_t Bs[128][72];
  const int tid  = threadIdx.x;
  const int lane = tid & 63;
  const int wid  = tid >> 6;
  const int wm   = wid >> 1, wn = wid & 1;   // 2x2 wave grid, 64x64 out each
  const int srow = tid >> 3;                 // staging row 0..31
  const int scol = (tid & 7) * 8;            // staging col chunk
  const long abase = (long)blockIdx.x * 128 * K;
  const long bbase = (long)blockIdx.y * 128 * K;
  const int rsel = lane & 15;
  const int koff = (lane >> 4) * 8;
  f32x4 acc[4][4] = {};

  for (int k0 = 0; k0 < K; k0 += 64) {
    __syncthreads();
#pragma unroll
    for (int p = 0; p < 4; p++) {
      const int row = p * 32 + srow;
      *(uint4*)(&As[row][scol]) = *(const uint4*)(&A [abase + (long)row * K + k0 + scol]);
      *(uint4*)(&Bs[row][scol]) = *(const uint4*)(&BT[bbase + (long)row * K + k0 + scol]);
    }
    __syncthreads();
#pragma unroll
    for (int kk = 0; kk < 64; kk += 32) {
      bf16x8 af[4], bfr[4];
#pragma unroll
      for (int m = 0; m < 4; m++) af[m]  = *(const bf16x8*)(&As[wm*64 + m*16 + rsel][kk + koff]);
#pragma unroll
      for (int n = 0; n < 4; n++) bfr[n] = *(const bf16x8*)(&Bs[wn*64 + n*16 + rsel][kk + koff]);
#pragma unroll
      for (int m = 0; m < 4; m++)
#pragma unroll
        for (int n = 0; n < 4; n++)
          asm("v_mfma_f32_16x16x32_bf16 %0, %1, %2, %0"
              : "+v"(acc[m][n]) : "v"(af[m]), "v"(bfr[n]));
    }
  }

  const int rbase = blockIdx.x * 128 + wm * 64 + (lane >> 4) * 4;
  const int cbase = blockIdx.y * 128 + wn * 64 + (lane & 15);
#pragma unroll
  for (int m = 0; m < 4; m++) {
#pragma unroll
    for (int n = 0; n < 4; n++) {
      const int gn = cbase + n * 16;
#pragma unroll
      for (int j = 0; j < 4; j++) {
        const int gm = rbase + m * 16 + j;
        const float v = acc[m][n][j];
        if (EPI == 1) {
          Cf[(long)gm * N + gn] = v;
        } else {
          if (gn < DIM) {
            Cq[(long)gm * DIM + gn] = f2bf(v);
          } else {
            const int x = gn - DIM;
            const int hkv = (x >> 6) & 3;
            const int d = x & 63;
            const int b = gm >> 11;
            const int t = gm & (TSEQ - 1);
            if (x < 256) Ck[((long)(b * NKV + hkv) * TSEQ + t) * HD + d] = f2bf(v);
            else         Cv[((long)(b * NKV + hkv) * HD + d) * TSEQ + t] = f2bf(v);
          }
        }
      }
    }
  }
}

// ---------------- RoPE ----------------
#define LOG1E4_D32 0.2878231366242557f   // ln(10000)/32

__global__ void rope_q_k(ushort_t* __restrict__ q) {
  const int idx = blockIdx.x * 256 + threadIdx.x;  // MROWS*NH*32 threads
  const int m  = idx >> 10;
  const int rr = idx & 1023;
  const int h  = rr >> 5;
  const int d  = rr & 31;
  const int t  = m & (TSEQ - 1);
  const float ang = (float)t * __expf(-(float)d * LOG1E4_D32);
  float s_, c_;
  __sincosf(ang, &s_, &c_);
  const long base = (long)m * DIM + h * 64 + d;
  const float q0 = bflo2f(q[base]);
  const float q1 = bflo2f(q[base + 32]);
  q[base]      = f2bf(q0 * c_ - q1 * s_);
  q[base + 32] = f2bf(q1 * c_ + q0 * s_);
}

__global__ void rope_k_k(ushort_t* __restrict__ k) {
  const int idx = blockIdx.x * 256 + threadIdx.x;  // BATCH*NKV*TSEQ*32 threads
  const int row = idx >> 5;
  const int d   = idx & 31;
  const int t   = row & (TSEQ - 1);
  const float ang = (float)t * __expf(-(float)d * LOG1E4_D32);
  float s_, c_;
  __sincosf(ang, &s_, &c_);
  const long base = (long)row * HD + d;
  const float k0 = bflo2f(k[base]);
  const float k1 = bflo2f(k[base + 32]);
  k[base]      = f2bf(k0 * c_ - k1 * s_);
  k[base + 32] = f2bf(k1 * c_ + k0 * s_);
}

// ---------------- attention: one wave per (b,h,t) row ----------------
__global__ __launch_bounds__(256, 2) void attn_k(
    const ushort_t* __restrict__ q, const ushort_t* __restrict__ k,
    const ushort_t* __restrict__ vt, ushort_t* __restrict__ o)
{
  __shared__ float p_lds[4][TSEQ];
  const int lane = threadIdx.x & 63;
  const int wid  = threadIdx.x >> 6;
  const int row  = blockIdx.x * 4 + wid;   // (b*NH + h)*TSEQ + t
  const int t    = row & (TSEQ - 1);
  const int bh   = row >> 11;
  const int h    = bh & (NH - 1);
  const int b    = bh >> 5;
  const int hkv  = h >> 3;

  float qv[64];
  {
    const uint4* qr = (const uint4*)(q + (long)(b * TSEQ + t) * DIM + h * 64);
#pragma unroll
    for (int c = 0; c < 8; c++) {
      const uint4 rv = qr[c];
      qv[c*8+0] = bflo2f(rv.x) * 0.125f; qv[c*8+1] = bfhi2f(rv.x) * 0.125f;
      qv[c*8+2] = bflo2f(rv.y) * 0.125f; qv[c*8+3] = bfhi2f(rv.y) * 0.125f;
      qv[c*8+4] = bflo2f(rv.z) * 0.125f; qv[c*8+5] = bfhi2f(rv.z) * 0.125f;
      qv[c*8+6] = bflo2f(rv.w) * 0.125f; qv[c*8+7] = bfhi2f(rv.w) * 0.125f;
    }
  }

  const int nk = t + 1;
  const ushort_t* kbase = k + (long)(b * NKV + hkv) * TSEQ * HD;
  float sc[32];
  float mx = -1e30f;
#pragma unroll
  for (int i = 0; i < 32; i++) {
    const int j = i * 64 + lane;
    float s = -1e30f;
    if (j < nk) {
      const uint4* kr = (const uint4*)(kbase + (long)j * HD);
      float dot = 0.f;
#pragma unroll
      for (int c = 0; c < 8; c++) {
        const uint4 rv = kr[c];
        dot = fmaf(bflo2f(rv.x), qv[c*8+0], dot);
        dot = fmaf(bfhi2f(rv.x), qv[c*8+1], dot);
        dot = fmaf(bflo2f(rv.y), qv[c*8+2], dot);
        dot = fmaf(bfhi2f(rv.y), qv[c*8+3], dot);
        dot = fmaf(bflo2f(rv.z), qv[c*8+4], dot);
        dot = fmaf(bfhi2f(rv.z), qv[c*8+5], dot);
        dot = fmaf(bflo2f(rv.w), qv[c*8+6], dot);
        dot = fmaf(bfhi2f(rv.w), qv[c*8+7], dot);
      }
      s = dot;
    }
    sc[i] = s;
    mx = fmaxf(mx, s);
  }
#pragma unroll
  for (int off = 32; off > 0; off >>= 1) mx = fmaxf(mx, __shfl_xor(mx, off, 64));

  float lsum = 0.f;
#pragma unroll
  for (int i = 0; i < 32; i++) {
    const float p = __expf(sc[i] - mx);   // invalid keys: exp(-1e30 - mx) = 0
    lsum += p;
    p_lds[wid][i * 64 + lane] = p;
  }
#pragma unroll
  for (int off = 32; off > 0; off >>= 1) lsum += __shfl_xor(lsum, off, 64);
  const float inv = 1.f / lsum;
  __syncthreads();

  const uint4* vr = (const uint4*)(vt + ((long)(b * NKV + hkv) * HD + lane) * TSEQ);
  const float4* pf = (const float4*)(&p_lds[wid][0]);
  float accv = 0.f;
  const int nch = (nk + 7) >> 3;
  for (int c = 0; c < nch; c++) {
    const uint4 rv = vr[c];
    const float4 pa = pf[c*2];
    const float4 pb = pf[c*2+1];
    accv = fmaf(bflo2f(rv.x), pa.x, accv);
    accv = fmaf(bfhi2f(rv.x), pa.y, accv);
    accv = fmaf(bflo2f(rv.y), pa.z, accv);
    accv = fmaf(bfhi2f(rv.y), pa.w, accv);
    accv = fmaf(bflo2f(rv.z), pb.x, accv);
    accv = fmaf(bfhi2f(rv.z), pb.y, accv);
    accv = fmaf(bflo2f(rv.w), pb.z, accv);
    accv = fmaf(bfhi2f(rv.w), pb.w, accv);
  }
  o[(long)(b * TSEQ + t) * DIM + h * 64 + lane] = f2bf(accv * inv);
}

// ---------------- launch ----------------
extern "C" void kernel_launch(void* const* d_in, const int* in_sizes, int n_in,
                              void* d_out, int out_size, void* d_ws, size_t ws_size,
                              hipStream_t stream) {
  const float* x  = (const float*)d_in[0];
  const float* wq = (const float*)d_in[1];
  const float* wk = (const float*)d_in[2];
  const float* wv = (const float*)d_in[3];
  const float* wo = (const float*)d_in[4];
  float* out = (float*)d_out;

  ushort_t* ws = (ushort_t*)d_ws;
  const long NXB = (long)MROWS * DIM;               // 8388608
  ushort_t* xb   = ws;
  ushort_t* wtq  = xb  + NXB;                       // [2560][2048]
  ushort_t* woT  = wtq + (long)NQKV * DIM;          // [2048][2048]
  ushort_t* qws  = woT + (long)DIM * DIM;           // [4096][2048]
  ushort_t* kws  = qws + NXB;                       // [B,Hkv,T,D]
  ushort_t* vtws = kws + (long)BATCH * NKV * TSEQ * HD;  // [B,Hkv,D,T]
  ushort_t* aws  = vtws + (long)BATCH * NKV * TSEQ * HD; // [4096][2048]

  cast_bf16_k<<<(int)(NXB / 1024), 256, 0, stream>>>(x, xb, (int)(NXB / 4));
  transpose_cast<<<dim3(64, 64), 256, 0, stream>>>(wq, wtq, DIM, DIM);
  transpose_cast<<<dim3(64, 8),  256, 0, stream>>>(wk, wtq + (long)DIM  * DIM, DIM, 256);
  transpose_cast<<<dim3(64, 8),  256, 0, stream>>>(wv, wtq + (long)2304 * DIM, DIM, 256);
  transpose_cast<<<dim3(64, 64), 256, 0, stream>>>(wo, woT, DIM, DIM);

  gemm_bt<0><<<dim3(32, 20), 256, 0, stream>>>(xb, wtq, MROWS, NQKV, DIM,
                                               nullptr, qws, kws, vtws);
  rope_q_k<<<(MROWS * NH * 32) / 256, 256, 0, stream>>>(qws);
  rope_k_k<<<(BATCH * NKV * TSEQ * 32) / 256, 256, 0, stream>>>(kws);

  attn_k<<<(BATCH * NH * TSEQ) / 4, 256, 0, stream>>>(qws, kws, vtws, aws);

  gemm_bt<1><<<dim3(32, 16), 256, 0, stream>>>(aws, woT, MROWS, DIM, DIM,
                                               out, nullptr, nullptr, nullptr);
}

// Round 3
// 368.385 us; speedup vs baseline: 11.0730x; 11.0730x over previous
//
#include <hip/hip_runtime.h>
#include <hip/hip_bf16.h>
#include <stdint.h>

#define DIM 2048
#define TSEQ 2048
#define BATCH 2
#define NH 32
#define NKV 4
#define HD 64
#define MROWS (BATCH*TSEQ)   // 4096
#define NQKV 2560            // 2048 q + 256 k + 256 v

typedef __attribute__((ext_vector_type(4))) float f32x4;
typedef __attribute__((ext_vector_type(8))) __bf16 bf16x8;
typedef unsigned short ushort_t;

__device__ __forceinline__ float bflo2f(unsigned int w) {
  union { unsigned int i; float f; } c; c.i = w << 16; return c.f;
}
__device__ __forceinline__ float bfhi2f(unsigned int w) {
  union { unsigned int i; float f; } c; c.i = w & 0xffff0000u; return c.f;
}
__device__ __forceinline__ unsigned short f2bf(float f) {
  union { float f; unsigned int i; } c; c.f = f;
  unsigned int x = c.i;
  x += 0x7fffu + ((x >> 16) & 1u);   // round to nearest even
  return (unsigned short)(x >> 16);
}

// ---------------- cast x (f32 -> bf16), 4 elems/thread ----------------
__global__ void cast_bf16_k(const float* __restrict__ in, ushort_t* __restrict__ out, int n4) {
  const int i = blockIdx.x * 256 + threadIdx.x;
  if (i >= n4) return;
  const float4 v = ((const float4*)in)[i];
  uint2 p;
  p.x = (unsigned int)f2bf(v.x) | ((unsigned int)f2bf(v.y) << 16);
  p.y = (unsigned int)f2bf(v.z) | ((unsigned int)f2bf(v.w) << 16);
  ((uint2*)out)[i] = p;
}

// ---------------- transpose-cast: w[K][N] f32 -> wt[N][K] bf16 ----------------
__global__ void transpose_cast(const float* __restrict__ w, ushort_t* __restrict__ wt, int K, int N) {
  __shared__ float tile[32][33];
  const int bk = blockIdx.x * 32;
  const int bn = blockIdx.y * 32;
  const int tx = threadIdx.x & 31;
  const int ty = threadIdx.x >> 5;  // 0..7
#pragma unroll
  for (int p = 0; p < 4; p++) {
    const int r = ty + p * 8;
    tile[r][tx] = w[(long)(bk + r) * N + bn + tx];
  }
  __syncthreads();
#pragma unroll
  for (int p = 0; p < 4; p++) {
    const int r = ty + p * 8;
    wt[(long)(bn + r) * K + bk + tx] = f2bf(tile[tx][r]);
  }
}

// ---------------- bf16 MFMA GEMM: C[M][N] = A[M][K] * BT[N][K]^T ----------------
// EPI 0: scatter to Q [B,T,H*D] bf16, K [B,Hkv,T,D] bf16, V^T [B,Hkv,D,T] bf16
// EPI 1: plain f32 C
template<int EPI>
__global__ __launch_bounds__(256, 2) void gemm_bt(
    const ushort_t* __restrict__ A, const ushort_t* __restrict__ BT,
    int M, int N, int K,
    float* __restrict__ Cf, ushort_t* __restrict__ Cq,
    ushort_t* __restrict__ Ck, ushort_t* __restrict__ Cv)
{
  __shared__ __align__(16) ushort_t As[128][72];
  __shared__ __align__(16) ushort_t Bs[128][72];
  const int tid  = threadIdx.x;
  const int lane = tid & 63;
  const int wid  = tid >> 6;
  const int wm   = wid >> 1, wn = wid & 1;   // 2x2 wave grid, 64x64 out each
  const int srow = tid >> 3;                 // staging row 0..31
  const int scol = (tid & 7) * 8;            // staging col chunk
  const long abase = (long)blockIdx.x * 128 * K;
  const long bbase = (long)blockIdx.y * 128 * K;
  const int rsel = lane & 15;
  const int koff = (lane >> 4) * 8;
  f32x4 acc[4][4] = {};

  for (int k0 = 0; k0 < K; k0 += 64) {
    __syncthreads();
#pragma unroll
    for (int p = 0; p < 4; p++) {
      const int row = p * 32 + srow;
      *(uint4*)(&As[row][scol]) = *(const uint4*)(&A [abase + (long)row * K + k0 + scol]);
      *(uint4*)(&Bs[row][scol]) = *(const uint4*)(&BT[bbase + (long)row * K + k0 + scol]);
    }
    __syncthreads();
#pragma unroll
    for (int kk = 0; kk < 64; kk += 32) {
      bf16x8 af[4], bfr[4];
#pragma unroll
      for (int m = 0; m < 4; m++) af[m]  = *(const bf16x8*)(&As[wm*64 + m*16 + rsel][kk + koff]);
#pragma unroll
      for (int n = 0; n < 4; n++) bfr[n] = *(const bf16x8*)(&Bs[wn*64 + n*16 + rsel][kk + koff]);
#pragma unroll
      for (int m = 0; m < 4; m++)
#pragma unroll
        for (int n = 0; n < 4; n++)
          acc[m][n] = __builtin_amdgcn_mfma_f32_16x16x32_bf16(af[m], bfr[n], acc[m][n], 0, 0, 0);
    }
  }

  const int rbase = blockIdx.x * 128 + wm * 64 + (lane >> 4) * 4;
  const int cbase = blockIdx.y * 128 + wn * 64 + (lane & 15);
#pragma unroll
  for (int m = 0; m < 4; m++) {
#pragma unroll
    for (int n = 0; n < 4; n++) {
      const int gn = cbase + n * 16;
#pragma unroll
      for (int j = 0; j < 4; j++) {
        const int gm = rbase + m * 16 + j;
        const float v = acc[m][n][j];
        if (EPI == 1) {
          Cf[(long)gm * N + gn] = v;
        } else {
          if (gn < DIM) {
            Cq[(long)gm * DIM + gn] = f2bf(v);
          } else {
            const int x = gn - DIM;
            const int hkv = (x >> 6) & 3;
            const int d = x & 63;
            const int b = gm >> 11;
            const int t = gm & (TSEQ - 1);
            if (x < 256) Ck[((long)(b * NKV + hkv) * TSEQ + t) * HD + d] = f2bf(v);
            else         Cv[((long)(b * NKV + hkv) * HD + d) * TSEQ + t] = f2bf(v);
          }
        }
      }
    }
  }
}

// ---------------- RoPE (Q also folds in the 1/sqrt(HD)=0.125 attention scale) ----------------
#define LOG1E4_D32 0.2878231366242557f   // ln(10000)/32

__global__ void rope_q_k(ushort_t* __restrict__ q) {
  const int idx = blockIdx.x * 256 + threadIdx.x;  // MROWS*NH*32 threads
  const int m  = idx >> 10;
  const int rr = idx & 1023;
  const int h  = rr >> 5;
  const int d  = rr & 31;
  const int t  = m & (TSEQ - 1);
  const float ang = (float)t * __expf(-(float)d * LOG1E4_D32);
  float s_, c_;
  __sincosf(ang, &s_, &c_);
  const long base = (long)m * DIM + h * 64 + d;
  const float q0 = bflo2f(q[base]);
  const float q1 = bflo2f(q[base + 32]);
  q[base]      = f2bf((q0 * c_ - q1 * s_) * 0.125f);
  q[base + 32] = f2bf((q1 * c_ + q0 * s_) * 0.125f);
}

__global__ void rope_k_k(ushort_t* __restrict__ k) {
  const int idx = blockIdx.x * 256 + threadIdx.x;  // BATCH*NKV*TSEQ*32 threads
  const int row = idx >> 5;
  const int d   = idx & 31;
  const int t   = row & (TSEQ - 1);
  const float ang = (float)t * __expf(-(float)d * LOG1E4_D32);
  float s_, c_;
  __sincosf(ang, &s_, &c_);
  const long base = (long)row * HD + d;
  const float k0 = bflo2f(k[base]);
  const float k1 = bflo2f(k[base + 32]);
  k[base]      = f2bf(k0 * c_ - k1 * s_);
  k[base + 32] = f2bf(k1 * c_ + k0 * s_);
}

// ---------------- MFMA flash attention ----------------
// Grid: (B*NH)*(TSEQ/64) blocks, 256 threads = 4 waves, wave w owns q rows
// [qbase+16w, qbase+16w+16). KV blocks of 64 staged in LDS; online softmax.
// MFMA 16x16x32 layouts (verified by gemm_bt on-device):
//   A-frag: lane holds A[row=lane&15][k=(lane>>4)*8+j]
//   B-frag: lane holds BT[n=lane&15][k=(lane>>4)*8+j]  (BT = B^T rows)
//   C:      lane holds C[row=(lane>>4)*4+j][col=lane&15]
__global__ __launch_bounds__(256, 2) void attn_mfma(
    const ushort_t* __restrict__ q, const ushort_t* __restrict__ k,
    const ushort_t* __restrict__ vt, ushort_t* __restrict__ o)
{
  __shared__ __align__(16) ushort_t Ks[64][72];       // [key][d]
  __shared__ __align__(16) ushort_t Vs[64][72];       // [d][key]  (V^T)
  __shared__ __align__(16) ushort_t Ps[4][16][72];    // per-wave P [q][key]

  const int tid  = threadIdx.x;
  const int lane = tid & 63;
  const int wid  = tid >> 6;
  const int l15  = lane & 15;
  const int lg   = lane >> 4;         // 0..3

  const int nqt = TSEQ / 64;          // 32
  const int bh  = blockIdx.x / nqt;
  const int qt  = blockIdx.x - bh * nqt;
  const int h   = bh & (NH - 1);
  const int b   = bh >> 5;
  const int hkv = h >> 3;
  const int qbase = qt * 64;

  // Q A-fragments (2 k-chunks of 32), loaded once. Q is pre-scaled by 0.125.
  bf16x8 qf[2];
  {
    const ushort_t* qp = q + ((long)(b * TSEQ) + qbase + wid * 16 + l15) * DIM + h * 64 + lg * 8;
    qf[0] = *(const bf16x8*)(qp);
    qf[1] = *(const bf16x8*)(qp + 32);
  }

  const ushort_t* kb_ = k  + (long)(b * NKV + hkv) * TSEQ * HD;
  const ushort_t* vb_ = vt + (long)(b * NKV + hkv) * HD * TSEQ;

  float m_[4], l_[4];
  f32x4 o_[4] = {};
#pragma unroll
  for (int j = 0; j < 4; j++) { m_[j] = -1e30f; l_[j] = 0.f; }

  const int srow = tid >> 2;          // 0..63
  const int sc   = (tid & 3) * 16;    // ushort offset within 64-wide row

  for (int kbv = 0; kbv <= qt; kbv++) {
    const int kb0 = kbv * 64;
    __syncthreads();
    *(uint4*)(&Ks[srow][sc])     = *(const uint4*)(&kb_[(long)(kb0 + srow) * HD + sc]);
    *(uint4*)(&Ks[srow][sc + 8]) = *(const uint4*)(&kb_[(long)(kb0 + srow) * HD + sc + 8]);
    *(uint4*)(&Vs[srow][sc])     = *(const uint4*)(&vb_[(long)srow * TSEQ + kb0 + sc]);
    *(uint4*)(&Vs[srow][sc + 8]) = *(const uint4*)(&vb_[(long)srow * TSEQ + kb0 + sc + 8]);
    __syncthreads();

    // S = Q K^T for 4 key-tiles of 16
    f32x4 st[4] = {};
#pragma unroll
    for (int kt = 0; kt < 4; kt++) {
#pragma unroll
      for (int c = 0; c < 2; c++) {
        const bf16x8 kf = *(const bf16x8*)(&Ks[kt * 16 + l15][c * 32 + lg * 8]);
        st[kt] = __builtin_amdgcn_mfma_f32_16x16x32_bf16(qf[c], kf, st[kt], 0, 0, 0);
      }
    }

    // causal mask (only the diagonal KV block needs it)
    if (kbv == qt) {
#pragma unroll
      for (int kt = 0; kt < 4; kt++) {
        const int kg = kb0 + kt * 16 + l15;
#pragma unroll
        for (int j = 0; j < 4; j++) {
          const int qg = qbase + wid * 16 + lg * 4 + j;
          if (kg > qg) st[kt][j] = -1e30f;
        }
      }
    }

    // online softmax: row max -> alpha, P = exp(S - m), row sum
    float mnew[4], alpha[4];
#pragma unroll
    for (int j = 0; j < 4; j++) {
      float rm = fmaxf(fmaxf(st[0][j], st[1][j]), fmaxf(st[2][j], st[3][j]));
      rm = fmaxf(rm, __shfl_xor(rm, 1, 64));
      rm = fmaxf(rm, __shfl_xor(rm, 2, 64));
      rm = fmaxf(rm, __shfl_xor(rm, 4, 64));
      rm = fmaxf(rm, __shfl_xor(rm, 8, 64));
      mnew[j] = fmaxf(m_[j], rm);
      alpha[j] = __expf(m_[j] - mnew[j]);
      m_[j] = mnew[j];
    }
    float rs[4] = {0.f, 0.f, 0.f, 0.f};
#pragma unroll
    for (int kt = 0; kt < 4; kt++) {
#pragma unroll
      for (int j = 0; j < 4; j++) {
        const float p = __expf(st[kt][j] - mnew[j]);
        rs[j] += p;
        Ps[wid][lg * 4 + j][kt * 16 + l15] = f2bf(p);
      }
    }
#pragma unroll
    for (int j = 0; j < 4; j++) {
      float s = rs[j];
      s += __shfl_xor(s, 1, 64);
      s += __shfl_xor(s, 2, 64);
      s += __shfl_xor(s, 4, 64);
      s += __shfl_xor(s, 8, 64);
      l_[j] = l_[j] * alpha[j] + s;
    }

    // rescale O then O += P V  (P read back from LDS in A-frag layout)
#pragma unroll
    for (int nt = 0; nt < 4; nt++)
#pragma unroll
      for (int j = 0; j < 4; j++) o_[nt][j] *= alpha[j];

#pragma unroll
    for (int c = 0; c < 2; c++) {
      const bf16x8 pa = *(const bf16x8*)(&Ps[wid][l15][c * 32 + lg * 8]);
#pragma unroll
      for (int nt = 0; nt < 4; nt++) {
        const bf16x8 vf = *(const bf16x8*)(&Vs[nt * 16 + l15][c * 32 + lg * 8]);
        o_[nt] = __builtin_amdgcn_mfma_f32_16x16x32_bf16(pa, vf, o_[nt], 0, 0, 0);
      }
    }
  }

  // epilogue: normalize and store bf16
  const long orow = (long)(b * TSEQ) + qbase + wid * 16;
#pragma unroll
  for (int j = 0; j < 4; j++) {
    const float inv = 1.f / l_[j];
#pragma unroll
    for (int nt = 0; nt < 4; nt++)
      o[(orow + lg * 4 + j) * DIM + h * 64 + nt * 16 + l15] = f2bf(o_[nt][j] * inv);
  }
}

// ---------------- launch ----------------
extern "C" void kernel_launch(void* const* d_in, const int* in_sizes, int n_in,
                              void* d_out, int out_size, void* d_ws, size_t ws_size,
                              hipStream_t stream) {
  const float* x  = (const float*)d_in[0];
  const float* wq = (const float*)d_in[1];
  const float* wk = (const float*)d_in[2];
  const float* wv = (const float*)d_in[3];
  const float* wo = (const float*)d_in[4];
  float* out = (float*)d_out;

  ushort_t* ws = (ushort_t*)d_ws;
  const long NXB = (long)MROWS * DIM;               // 8388608
  ushort_t* xb   = ws;
  ushort_t* wtq  = xb  + NXB;                       // [2560][2048]
  ushort_t* woT  = wtq + (long)NQKV * DIM;          // [2048][2048]
  ushort_t* qws  = woT + (long)DIM * DIM;           // [4096][2048]
  ushort_t* kws  = qws + NXB;                       // [B,Hkv,T,D]
  ushort_t* vtws = kws + (long)BATCH * NKV * TSEQ * HD;  // [B,Hkv,D,T]
  ushort_t* aws  = vtws + (long)BATCH * NKV * TSEQ * HD; // [4096][2048]

  cast_bf16_k<<<(int)(NXB / 1024), 256, 0, stream>>>(x, xb, (int)(NXB / 4));
  transpose_cast<<<dim3(64, 64), 256, 0, stream>>>(wq, wtq, DIM, DIM);
  transpose_cast<<<dim3(64, 8),  256, 0, stream>>>(wk, wtq + (long)DIM  * DIM, DIM, 256);
  transpose_cast<<<dim3(64, 8),  256, 0, stream>>>(wv, wtq + (long)2304 * DIM, DIM, 256);
  transpose_cast<<<dim3(64, 64), 256, 0, stream>>>(wo, woT, DIM, DIM);

  gemm_bt<0><<<dim3(32, 20), 256, 0, stream>>>(xb, wtq, MROWS, NQKV, DIM,
                                               nullptr, qws, kws, vtws);
  rope_q_k<<<(MROWS * NH * 32) / 256, 256, 0, stream>>>(qws);
  rope_k_k<<<(BATCH * NKV * TSEQ * 32) / 256, 256, 0, stream>>>(kws);

  attn_mfma<<<BATCH * NH * (TSEQ / 64), 256, 0, stream>>>(qws, kws, vtws, aws);

  gemm_bt<1><<<dim3(32, 16), 256, 0, stream>>>(aws, woT, MROWS, DIM, DIM,
                                               out, nullptr, nullptr, nullptr);
}

// Round 4
// 263.772 us; speedup vs baseline: 15.4646x; 1.3966x over previous
//
#include <hip/hip_runtime.h>
#include <hip/hip_bf16.h>
#include <stdint.h>

#define DIM 2048
#define TSEQ 2048
#define BATCH 2
#define NH 32
#define NKV 4
#define HD 64
#define MROWS (BATCH*TSEQ)   // 4096
#define NQKV 2560            // 2048 q + 256 k + 256 v

typedef __attribute__((ext_vector_type(4))) float f32x4;
typedef __attribute__((ext_vector_type(8))) __bf16 bf16x8;
typedef unsigned short ushort_t;

__device__ __forceinline__ float bflo2f(unsigned int w) {
  union { unsigned int i; float f; } c; c.i = w << 16; return c.f;
}
__device__ __forceinline__ float bfhi2f(unsigned int w) {
  union { unsigned int i; float f; } c; c.i = w & 0xffff0000u; return c.f;
}
__device__ __forceinline__ unsigned short f2bf(float f) {
  union { float f; unsigned int i; } c; c.f = f;
  unsigned int x = c.i;
  x += 0x7fffu + ((x >> 16) & 1u);   // round to nearest even
  return (unsigned short)(x >> 16);
}

// ---------------- cast x (f32 -> bf16), 4 elems/thread ----------------
__global__ void cast_bf16_k(const float* __restrict__ in, ushort_t* __restrict__ out, int n4) {
  const int i = blockIdx.x * 256 + threadIdx.x;
  if (i >= n4) return;
  const float4 v = ((const float4*)in)[i];
  uint2 p;
  p.x = (unsigned int)f2bf(v.x) | ((unsigned int)f2bf(v.y) << 16);
  p.y = (unsigned int)f2bf(v.z) | ((unsigned int)f2bf(v.w) << 16);
  ((uint2*)out)[i] = p;
}

// ---------------- transpose-cast: w[K][N] f32 -> wt[N][K] bf16 ----------------
__global__ void transpose_cast(const float* __restrict__ w, ushort_t* __restrict__ wt, int K, int N) {
  __shared__ float tile[32][33];
  const int bk = blockIdx.x * 32;
  const int bn = blockIdx.y * 32;
  const int tx = threadIdx.x & 31;
  const int ty = threadIdx.x >> 5;  // 0..7
#pragma unroll
  for (int p = 0; p < 4; p++) {
    const int r = ty + p * 8;
    tile[r][tx] = w[(long)(bk + r) * N + bn + tx];
  }
  __syncthreads();
#pragma unroll
  for (int p = 0; p < 4; p++) {
    const int r = ty + p * 8;
    wt[(long)(bn + r) * K + bk + tx] = f2bf(tile[tx][r]);
  }
}

// ---------------- bf16 MFMA GEMM: C[M][N] = A[M][K] * BT[N][K]^T ----------------
template<int EPI>
__global__ __launch_bounds__(256, 2) void gemm_bt(
    const ushort_t* __restrict__ A, const ushort_t* __restrict__ BT,
    int M, int N, int K,
    float* __restrict__ Cf, ushort_t* __restrict__ Cq,
    ushort_t* __restrict__ Ck, ushort_t* __restrict__ Cv)
{
  __shared__ __align__(16) ushort_t As[128][72];
  __shared__ __align__(16) ushort_t Bs[128][72];
  const int tid  = threadIdx.x;
  const int lane = tid & 63;
  const int wid  = tid >> 6;
  const int wm   = wid >> 1, wn = wid & 1;   // 2x2 wave grid, 64x64 out each
  const int srow = tid >> 3;                 // staging row 0..31
  const int scol = (tid & 7) * 8;            // staging col chunk
  const long abase = (long)blockIdx.x * 128 * K;
  const long bbase = (long)blockIdx.y * 128 * K;
  const int rsel = lane & 15;
  const int koff = (lane >> 4) * 8;
  f32x4 acc[4][4] = {};

  for (int k0 = 0; k0 < K; k0 += 64) {
    __syncthreads();
#pragma unroll
    for (int p = 0; p < 4; p++) {
      const int row = p * 32 + srow;
      *(uint4*)(&As[row][scol]) = *(const uint4*)(&A [abase + (long)row * K + k0 + scol]);
      *(uint4*)(&Bs[row][scol]) = *(const uint4*)(&BT[bbase + (long)row * K + k0 + scol]);
    }
    __syncthreads();
#pragma unroll
    for (int kk = 0; kk < 64; kk += 32) {
      bf16x8 af[4], bfr[4];
#pragma unroll
      for (int m = 0; m < 4; m++) af[m]  = *(const bf16x8*)(&As[wm*64 + m*16 + rsel][kk + koff]);
#pragma unroll
      for (int n = 0; n < 4; n++) bfr[n] = *(const bf16x8*)(&Bs[wn*64 + n*16 + rsel][kk + koff]);
#pragma unroll
      for (int m = 0; m < 4; m++)
#pragma unroll
        for (int n = 0; n < 4; n++)
          acc[m][n] = __builtin_amdgcn_mfma_f32_16x16x32_bf16(af[m], bfr[n], acc[m][n], 0, 0, 0);
    }
  }

  const int rbase = blockIdx.x * 128 + wm * 64 + (lane >> 4) * 4;
  const int cbase = blockIdx.y * 128 + wn * 64 + (lane & 15);
#pragma unroll
  for (int m = 0; m < 4; m++) {
#pragma unroll
    for (int n = 0; n < 4; n++) {
      const int gn = cbase + n * 16;
#pragma unroll
      for (int j = 0; j < 4; j++) {
        const int gm = rbase + m * 16 + j;
        const float v = acc[m][n][j];
        if (EPI == 1) {
          Cf[(long)gm * N + gn] = v;
        } else {
          if (gn < DIM) {
            Cq[(long)gm * DIM + gn] = f2bf(v);
          } else {
            const int x = gn - DIM;
            const int hkv = (x >> 6) & 3;
            const int d = x & 63;
            const int b = gm >> 11;
            const int t = gm & (TSEQ - 1);
            if (x < 256) Ck[((long)(b * NKV + hkv) * TSEQ + t) * HD + d] = f2bf(v);
            else         Cv[((long)(b * NKV + hkv) * HD + d) * TSEQ + t] = f2bf(v);
          }
        }
      }
    }
  }
}

// ---------------- RoPE (Q also folds in the 1/sqrt(HD)=0.125 attention scale) ----------------
#define LOG1E4_D32 0.2878231366242557f   // ln(10000)/32

__global__ void rope_q_k(ushort_t* __restrict__ q) {
  const int idx = blockIdx.x * 256 + threadIdx.x;  // MROWS*NH*32 threads
  const int m  = idx >> 10;
  const int rr = idx & 1023;
  const int h  = rr >> 5;
  const int d  = rr & 31;
  const int t  = m & (TSEQ - 1);
  const float ang = (float)t * __expf(-(float)d * LOG1E4_D32);
  float s_, c_;
  __sincosf(ang, &s_, &c_);
  const long base = (long)m * DIM + h * 64 + d;
  const float q0 = bflo2f(q[base]);
  const float q1 = bflo2f(q[base + 32]);
  q[base]      = f2bf((q0 * c_ - q1 * s_) * 0.125f);
  q[base + 32] = f2bf((q1 * c_ + q0 * s_) * 0.125f);
}

__global__ void rope_k_k(ushort_t* __restrict__ k) {
  const int idx = blockIdx.x * 256 + threadIdx.x;  // BATCH*NKV*TSEQ*32 threads
  const int row = idx >> 5;
  const int d   = idx & 31;
  const int t   = row & (TSEQ - 1);
  const float ang = (float)t * __expf(-(float)d * LOG1E4_D32);
  float s_, c_;
  __sincosf(ang, &s_, &c_);
  const long base = (long)row * HD + d;
  const float k0 = bflo2f(k[base]);
  const float k1 = bflo2f(k[base + 32]);
  k[base]      = f2bf(k0 * c_ - k1 * s_);
  k[base + 32] = f2bf(k1 * c_ + k0 * s_);
}

// ---------------- MFMA flash attention (8 waves, QBLK=128, dbuf K/V) ----------------
// Grid: 64 bh * 16 q-tiles, 512 threads. Wave w owns q rows [qt*128+16w, +16).
// KV blocks of 64; double-buffered LDS; async-STAGE split (T14): next-tile
// global loads issued before the barrier, ds_write after compute (vmcnt there).
// One raw lgkmcnt(0)+s_barrier per iter: each wave drains its own LDS ops
// before the barrier; staging writes go to the opposite buffer (no WAR).
// Blocks scheduled in descending-work order (qt = 15 - bid/64).
__global__ __launch_bounds__(512, 4) void attn_mfma(
    const ushort_t* __restrict__ q, const ushort_t* __restrict__ k,
    const ushort_t* __restrict__ vt, ushort_t* __restrict__ o)
{
  __shared__ __align__(16) ushort_t Ks[2][64][72];    // [buf][key][d]
  __shared__ __align__(16) ushort_t Vs[2][64][72];    // [buf][d][key] (V^T)
  __shared__ __align__(16) ushort_t Ps[8][16][72];    // per-wave P [q][key]

  const int tid  = threadIdx.x;
  const int lane = tid & 63;
  const int wid  = tid >> 6;          // 0..7
  const int l15  = lane & 15;
  const int lg   = lane >> 4;         // 0..3

  const int bh  = blockIdx.x & 63;
  const int qt  = (TSEQ / 128 - 1) - (blockIdx.x >> 6);   // descending work
  const int h   = bh & (NH - 1);
  const int b   = bh >> 5;
  const int hkv = h >> 3;
  const int qbase = qt * 128;
  const int qw0   = qbase + wid * 16;

  // Q A-fragments (2 k-chunks of 32). Q is pre-scaled by 0.125.
  bf16x8 qf[2];
  {
    const ushort_t* qp = q + ((long)(b * TSEQ) + qw0 + l15) * DIM + h * 64 + lg * 8;
    qf[0] = *(const bf16x8*)(qp);
    qf[1] = *(const bf16x8*)(qp + 32);
  }

  const ushort_t* kb_ = k  + (long)(b * NKV + hkv) * TSEQ * HD;
  const ushort_t* vb_ = vt + (long)(b * NKV + hkv) * HD * TSEQ;

  float m_[4], l_[4];
  f32x4 o_[4] = {};
#pragma unroll
  for (int j = 0; j < 4; j++) { m_[j] = -1e30f; l_[j] = 0.f; }

  const int srow = tid >> 3;          // 0..63
  const int sc   = (tid & 7) * 8;     // ushort offset, one uint4 per thread

  const int nkv = 2 * (qt + 1);

  // prologue: stage KV tile 0 into buf 0
  {
    const uint4 kr = *(const uint4*)(&kb_[(long)srow * HD + sc]);
    const uint4 vr = *(const uint4*)(&vb_[(long)srow * TSEQ + sc]);
    *(uint4*)(&Ks[0][srow][sc]) = kr;
    *(uint4*)(&Vs[0][srow][sc]) = vr;
  }
  int cur = 0;

  for (int kbv = 0; kbv < nkv; kbv++) {
    const int kb0 = kbv * 64;
    const bool pf = (kbv + 1 < nkv);
    uint4 kr = {}, vr = {};
    if (pf) {   // issue next-tile loads early; vmcnt waited at the ds_write below
      kr = *(const uint4*)(&kb_[(long)(kb0 + 64 + srow) * HD + sc]);
      vr = *(const uint4*)(&vb_[(long)srow * TSEQ + kb0 + 64 + sc]);
    }
    // drain own LDS ops, then sync (no vmcnt drain -> prefetch stays in flight)
    asm volatile("s_waitcnt lgkmcnt(0)\n\ts_barrier" ::: "memory");

    if (kb0 <= qw0 + 15) {             // wave-uniform: this wave has live keys
      // S = Q K^T for 4 key-tiles of 16
      f32x4 st[4] = {};
#pragma unroll
      for (int kt = 0; kt < 4; kt++) {
#pragma unroll
        for (int c = 0; c < 2; c++) {
          const bf16x8 kf = *(const bf16x8*)(&Ks[cur][kt * 16 + l15][c * 32 + lg * 8]);
          st[kt] = __builtin_amdgcn_mfma_f32_16x16x32_bf16(qf[c], kf, st[kt], 0, 0, 0);
        }
      }

      if (kb0 + 63 > qw0) {            // diagonal block: causal mask
#pragma unroll
        for (int kt = 0; kt < 4; kt++) {
          const int kg = kb0 + kt * 16 + l15;
#pragma unroll
          for (int j = 0; j < 4; j++) {
            const int qg = qw0 + lg * 4 + j;
            if (kg > qg) st[kt][j] = -1e30f;
          }
        }
      }

      // online softmax
      float mnew[4], alpha[4];
#pragma unroll
      for (int j = 0; j < 4; j++) {
        float rm = fmaxf(fmaxf(st[0][j], st[1][j]), fmaxf(st[2][j], st[3][j]));
        rm = fmaxf(rm, __shfl_xor(rm, 1, 64));
        rm = fmaxf(rm, __shfl_xor(rm, 2, 64));
        rm = fmaxf(rm, __shfl_xor(rm, 4, 64));
        rm = fmaxf(rm, __shfl_xor(rm, 8, 64));
        mnew[j] = fmaxf(m_[j], rm);
        alpha[j] = __expf(m_[j] - mnew[j]);
        m_[j] = mnew[j];
      }
      float rs[4] = {0.f, 0.f, 0.f, 0.f};
#pragma unroll
      for (int kt = 0; kt < 4; kt++) {
#pragma unroll
        for (int j = 0; j < 4; j++) {
          const float p = __expf(st[kt][j] - mnew[j]);
          rs[j] += p;
          Ps[wid][lg * 4 + j][kt * 16 + l15] = f2bf(p);
        }
      }
#pragma unroll
      for (int j = 0; j < 4; j++) {
        float s = rs[j];
        s += __shfl_xor(s, 1, 64);
        s += __shfl_xor(s, 2, 64);
        s += __shfl_xor(s, 4, 64);
        s += __shfl_xor(s, 8, 64);
        l_[j] = l_[j] * alpha[j] + s;
      }

      // rescale O, then O += P V (P read back in A-frag layout)
#pragma unroll
      for (int nt = 0; nt < 4; nt++)
#pragma unroll
        for (int j = 0; j < 4; j++) o_[nt][j] *= alpha[j];

#pragma unroll
      for (int c = 0; c < 2; c++) {
        const bf16x8 pa = *(const bf16x8*)(&Ps[wid][l15][c * 32 + lg * 8]);
#pragma unroll
        for (int nt = 0; nt < 4; nt++) {
          const bf16x8 vf = *(const bf16x8*)(&Vs[cur][nt * 16 + l15][c * 32 + lg * 8]);
          o_[nt] = __builtin_amdgcn_mfma_f32_16x16x32_bf16(pa, vf, o_[nt], 0, 0, 0);
        }
      }
    }

    if (pf) {   // write prefetched tile into the other buffer (vmcnt wait here)
      *(uint4*)(&Ks[cur ^ 1][srow][sc]) = kr;
      *(uint4*)(&Vs[cur ^ 1][srow][sc]) = vr;
    }
    cur ^= 1;
  }

  // epilogue: normalize and store bf16
  const long orow = (long)(b * TSEQ) + qw0;
#pragma unroll
  for (int j = 0; j < 4; j++) {
    const float inv = 1.f / l_[j];
#pragma unroll
    for (int nt = 0; nt < 4; nt++)
      o[(orow + lg * 4 + j) * DIM + h * 64 + nt * 16 + l15] = f2bf(o_[nt][j] * inv);
  }
}

// ---------------- launch ----------------
extern "C" void kernel_launch(void* const* d_in, const int* in_sizes, int n_in,
                              void* d_out, int out_size, void* d_ws, size_t ws_size,
                              hipStream_t stream) {
  const float* x  = (const float*)d_in[0];
  const float* wq = (const float*)d_in[1];
  const float* wk = (const float*)d_in[2];
  const float* wv = (const float*)d_in[3];
  const float* wo = (const float*)d_in[4];
  float* out = (float*)d_out;

  ushort_t* ws = (ushort_t*)d_ws;
  const long NXB = (long)MROWS * DIM;               // 8388608
  ushort_t* xb   = ws;
  ushort_t* wtq  = xb  + NXB;                       // [2560][2048]
  ushort_t* woT  = wtq + (long)NQKV * DIM;          // [2048][2048]
  ushort_t* qws  = woT + (long)DIM * DIM;           // [4096][2048]
  ushort_t* kws  = qws + NXB;                       // [B,Hkv,T,D]
  ushort_t* vtws = kws + (long)BATCH * NKV * TSEQ * HD;  // [B,Hkv,D,T]
  ushort_t* aws  = vtws + (long)BATCH * NKV * TSEQ * HD; // [4096][2048]

  cast_bf16_k<<<(int)(NXB / 1024), 256, 0, stream>>>(x, xb, (int)(NXB / 4));
  transpose_cast<<<dim3(64, 64), 256, 0, stream>>>(wq, wtq, DIM, DIM);
  transpose_cast<<<dim3(64, 8),  256, 0, stream>>>(wk, wtq + (long)DIM  * DIM, DIM, 256);
  transpose_cast<<<dim3(64, 8),  256, 0, stream>>>(wv, wtq + (long)2304 * DIM, DIM, 256);
  transpose_cast<<<dim3(64, 64), 256, 0, stream>>>(wo, woT, DIM, DIM);

  gemm_bt<0><<<dim3(32, 20), 256, 0, stream>>>(xb, wtq, MROWS, NQKV, DIM,
                                               nullptr, qws, kws, vtws);
  rope_q_k<<<(MROWS * NH * 32) / 256, 256, 0, stream>>>(qws);
  rope_k_k<<<(BATCH * NKV * TSEQ * 32) / 256, 256, 0, stream>>>(kws);

  attn_mfma<<<BATCH * NH * (TSEQ / 128), 512, 0, stream>>>(qws, kws, vtws, aws);

  gemm_bt<1><<<dim3(32, 16), 256, 0, stream>>>(aws, woT, MROWS, DIM, DIM,
                                               out, nullptr, nullptr, nullptr);
}

// Round 5
// 253.629 us; speedup vs baseline: 16.0831x; 1.0400x over previous
//
#include <hip/hip_runtime.h>
#include <hip/hip_bf16.h>
#include <stdint.h>

#define DIM 2048
#define TSEQ 2048
#define BATCH 2
#define NH 32
#define NKV 4
#define HD 64
#define MROWS (BATCH*TSEQ)   // 4096
#define NQKV 2560            // 2048 q + 256 k + 256 v

typedef __attribute__((ext_vector_type(4))) float f32x4;
typedef __attribute__((ext_vector_type(8))) __bf16 bf16x8;
typedef unsigned short ushort_t;

// async global->LDS, 16B/lane: LDS dest = wave-uniform base + lane*16
#define GLDS16(g, l) __builtin_amdgcn_global_load_lds( \
    (const __attribute__((address_space(1))) void*)(g), \
    (__attribute__((address_space(3))) void*)(l), 16, 0, 0)

__device__ __forceinline__ float bflo2f(unsigned int w) {
  union { unsigned int i; float f; } c; c.i = w << 16; return c.f;
}
__device__ __forceinline__ unsigned short f2bf(float f) {
  union { float f; unsigned int i; } c; c.f = f;
  unsigned int x = c.i;
  x += 0x7fffu + ((x >> 16) & 1u);   // RTNE
  return (unsigned short)(x >> 16);
}
__device__ __forceinline__ unsigned short f2bf_fast(float f) {
  union { float f; unsigned int i; } c; c.f = f;
  return (unsigned short)((c.i + 0x8000u) >> 16);   // round-half-up
}

// ---------------- cast x (f32 -> bf16), 4 elems/thread ----------------
__global__ void cast_bf16_k(const float* __restrict__ in, ushort_t* __restrict__ out, int n4) {
  const int i = blockIdx.x * 256 + threadIdx.x;
  if (i >= n4) return;
  const float4 v = ((const float4*)in)[i];
  uint2 p;
  p.x = (unsigned int)f2bf(v.x) | ((unsigned int)f2bf(v.y) << 16);
  p.y = (unsigned int)f2bf(v.z) | ((unsigned int)f2bf(v.w) << 16);
  ((uint2*)out)[i] = p;
}

// ---------------- transpose-cast: w[K][N] f32 -> wt[N][K] bf16 ----------------
__global__ void transpose_cast(const float* __restrict__ w, ushort_t* __restrict__ wt, int K, int N) {
  __shared__ float tile[32][33];
  const int bk = blockIdx.x * 32;
  const int bn = blockIdx.y * 32;
  const int tx = threadIdx.x & 31;
  const int ty = threadIdx.x >> 5;  // 0..7
#pragma unroll
  for (int p = 0; p < 4; p++) {
    const int r = ty + p * 8;
    tile[r][tx] = w[(long)(bk + r) * N + bn + tx];
  }
  __syncthreads();
#pragma unroll
  for (int p = 0; p < 4; p++) {
    const int r = ty + p * 8;
    wt[(long)(bn + r) * K + bk + tx] = f2bf(tile[tx][r]);
  }
}

// ---------------- bf16 MFMA GEMM: C[M][N] = A[M][K] * BT[N][K]^T ----------------
// LDS staged via global_load_lds width=16 (m97 structure): linear [128][64] tiles.
template<int EPI>
__global__ __launch_bounds__(256, 2) void gemm_bt(
    const ushort_t* __restrict__ A, const ushort_t* __restrict__ BT,
    int M, int N, int K,
    float* __restrict__ Cf, ushort_t* __restrict__ Cq,
    ushort_t* __restrict__ Ck, ushort_t* __restrict__ Cv)
{
  __shared__ __align__(16) ushort_t As[128][64];
  __shared__ __align__(16) ushort_t Bs[128][64];
  const int tid  = threadIdx.x;
  const int lane = tid & 63;
  const int wid  = tid >> 6;
  const int wm   = wid >> 1, wn = wid & 1;   // 2x2 wave grid, 64x64 out each
  const int l8   = lane >> 3;                // 0..7: row within an 8-row chunk
  const int c8   = (lane & 7) * 8;           // ushort col within a 128B row
  const long abase = (long)blockIdx.x * 128 * K;
  const long bbase = (long)blockIdx.y * 128 * K;
  const int rsel = lane & 15;
  const int koff = (lane >> 4) * 8;
  f32x4 acc[4][4] = {};

  for (int k0 = 0; k0 < K; k0 += 64) {
    __syncthreads();   // previous-iter LDS reads complete
#pragma unroll
    for (int i = 0; i < 4; i++) {
      const int r0 = wid * 32 + i * 8;       // 8-row chunk staged per call
      GLDS16(&A [abase + (long)(r0 + l8) * K + k0 + c8], &As[r0][0]);
      GLDS16(&BT[bbase + (long)(r0 + l8) * K + k0 + c8], &Bs[r0][0]);
    }
    __syncthreads();   // vmcnt(0) drains the global_load_lds queue
#pragma unroll
    for (int kk = 0; kk < 64; kk += 32) {
      bf16x8 af[4], bfr[4];
#pragma unroll
      for (int m = 0; m < 4; m++) af[m]  = *(const bf16x8*)(&As[wm*64 + m*16 + rsel][kk + koff]);
#pragma unroll
      for (int n = 0; n < 4; n++) bfr[n] = *(const bf16x8*)(&Bs[wn*64 + n*16 + rsel][kk + koff]);
#pragma unroll
      for (int m = 0; m < 4; m++)
#pragma unroll
        for (int n = 0; n < 4; n++)
          acc[m][n] = __builtin_amdgcn_mfma_f32_16x16x32_bf16(af[m], bfr[n], acc[m][n], 0, 0, 0);
    }
  }

  const int rbase = blockIdx.x * 128 + wm * 64 + (lane >> 4) * 4;
  const int cbase = blockIdx.y * 128 + wn * 64 + (lane & 15);
#pragma unroll
  for (int m = 0; m < 4; m++) {
#pragma unroll
    for (int n = 0; n < 4; n++) {
      const int gn = cbase + n * 16;
#pragma unroll
      for (int j = 0; j < 4; j++) {
        const int gm = rbase + m * 16 + j;
        const float v = acc[m][n][j];
        if (EPI == 1) {
          Cf[(long)gm * N + gn] = v;
        } else {
          if (gn < DIM) {
            Cq[(long)gm * DIM + gn] = f2bf(v);
          } else {
            const int x = gn - DIM;
            const int hkv = (x >> 6) & 3;
            const int d = x & 63;
            const int b = gm >> 11;
            const int t = gm & (TSEQ - 1);
            if (x < 256) Ck[((long)(b * NKV + hkv) * TSEQ + t) * HD + d] = f2bf(v);
            else         Cv[((long)(b * NKV + hkv) * HD + d) * TSEQ + t] = f2bf(v);
          }
        }
      }
    }
  }
}

// ---------------- RoPE ----------------
// Q scale folds 1/sqrt(HD) * log2(e) = 0.125 * 1.4426950 (exp2-domain softmax).
#define LOG1E4_D32 0.2878231366242557f   // ln(10000)/32
#define QSCALE 0.1803368801111243f

__global__ void rope_q_k(ushort_t* __restrict__ q) {
  const int idx = blockIdx.x * 256 + threadIdx.x;  // MROWS*NH*32 threads
  const int m  = idx >> 10;
  const int rr = idx & 1023;
  const int h  = rr >> 5;
  const int d  = rr & 31;
  const int t  = m & (TSEQ - 1);
  const float ang = (float)t * __expf(-(float)d * LOG1E4_D32);
  float s_, c_;
  __sincosf(ang, &s_, &c_);
  const long base = (long)m * DIM + h * 64 + d;
  const float q0 = bflo2f(q[base]);
  const float q1 = bflo2f(q[base + 32]);
  q[base]      = f2bf((q0 * c_ - q1 * s_) * QSCALE);
  q[base + 32] = f2bf((q1 * c_ + q0 * s_) * QSCALE);
}

__global__ void rope_k_k(ushort_t* __restrict__ k) {
  const int idx = blockIdx.x * 256 + threadIdx.x;  // BATCH*NKV*TSEQ*32 threads
  const int row = idx >> 5;
  const int d   = idx & 31;
  const int t   = row & (TSEQ - 1);
  const float ang = (float)t * __expf(-(float)d * LOG1E4_D32);
  float s_, c_;
  __sincosf(ang, &s_, &c_);
  const long base = (long)row * HD + d;
  const float k0 = bflo2f(k[base]);
  const float k1 = bflo2f(k[base + 32]);
  k[base]      = f2bf(k0 * c_ - k1 * s_);
  k[base + 32] = f2bf(k1 * c_ + k0 * s_);
}

// ---------------- MFMA flash attention (8 waves, QBLK=128, dbuf K/V) ----------------
// exp2-domain online softmax, shared running max per 4-row group, defer-max THR=8.
__global__ __launch_bounds__(512, 4) void attn_mfma(
    const ushort_t* __restrict__ q, const ushort_t* __restrict__ k,
    const ushort_t* __restrict__ vt, ushort_t* __restrict__ o)
{
  __shared__ __align__(16) ushort_t Ks[2][64][72];    // [buf][key][d]
  __shared__ __align__(16) ushort_t Vs[2][64][72];    // [buf][d][key] (V^T)
  __shared__ __align__(16) ushort_t Ps[8][16][76];    // per-wave P [q][key], pad 76

  const int tid  = threadIdx.x;
  const int lane = tid & 63;
  const int wid  = tid >> 6;          // 0..7
  const int l15  = lane & 15;
  const int lg   = lane >> 4;         // 0..3

  const int bh  = blockIdx.x & 63;
  const int qt  = (TSEQ / 128 - 1) - (blockIdx.x >> 6);   // descending work
  const int h   = bh & (NH - 1);
  const int b   = bh >> 5;
  const int hkv = h >> 3;
  const int qbase = qt * 128;
  const int qw0   = qbase + wid * 16;

  // Q A-fragments (2 k-chunks of 32). Q pre-scaled by 0.125*log2e.
  bf16x8 qf[2];
  {
    const ushort_t* qp = q + ((long)(b * TSEQ) + qw0 + l15) * DIM + h * 64 + lg * 8;
    qf[0] = *(const bf16x8*)(qp);
    qf[1] = *(const bf16x8*)(qp + 32);
  }

  const ushort_t* kb_ = k  + (long)(b * NKV + hkv) * TSEQ * HD;
  const ushort_t* vb_ = vt + (long)(b * NKV + hkv) * HD * TSEQ;

  float m_g = -1e30f;
  float l_[4] = {0.f, 0.f, 0.f, 0.f};
  f32x4 o_[4] = {};

  const int srow = tid >> 3;          // 0..63
  const int sc   = (tid & 7) * 8;     // ushort offset, one uint4 per thread

  const int nkv = 2 * (qt + 1);

  // prologue: stage KV tile 0 into buf 0
  {
    const uint4 kr = *(const uint4*)(&kb_[(long)srow * HD + sc]);
    const uint4 vr = *(const uint4*)(&vb_[(long)srow * TSEQ + sc]);
    *(uint4*)(&Ks[0][srow][sc]) = kr;
    *(uint4*)(&Vs[0][srow][sc]) = vr;
  }
  int cur = 0;

  for (int kbv = 0; kbv < nkv; kbv++) {
    const int kb0 = kbv * 64;
    const bool pf = (kbv + 1 < nkv);
    uint4 kr = {}, vr = {};
    if (pf) {   // issue next-tile loads early; vmcnt waited at the ds_write below
      kr = *(const uint4*)(&kb_[(long)(kb0 + 64 + srow) * HD + sc]);
      vr = *(const uint4*)(&vb_[(long)srow * TSEQ + kb0 + 64 + sc]);
    }
    // drain own LDS ops, then sync (no vmcnt drain -> prefetch stays in flight)
    asm volatile("s_waitcnt lgkmcnt(0)\n\ts_barrier" ::: "memory");

    if (kb0 <= qw0 + 15) {             // wave-uniform: this wave has live keys
      // S = Q K^T (exp2-domain logits), 4 key-tiles of 16
      f32x4 st[4] = {};
#pragma unroll
      for (int kt = 0; kt < 4; kt++) {
#pragma unroll
        for (int c = 0; c < 2; c++) {
          const bf16x8 kf = *(const bf16x8*)(&Ks[cur][kt * 16 + l15][c * 32 + lg * 8]);
          st[kt] = __builtin_amdgcn_mfma_f32_16x16x32_bf16(qf[c], kf, st[kt], 0, 0, 0);
        }
      }

      if (kb0 + 63 > qw0) {            // diagonal block: causal mask
#pragma unroll
        for (int kt = 0; kt < 4; kt++) {
          const int kg = kb0 + kt * 16 + l15;
#pragma unroll
          for (int j = 0; j < 4; j++) {
            const int qg = qw0 + lg * 4 + j;
            if (kg > qg) st[kt][j] = -1e30f;
          }
        }
      }

      // group max over this lane-group's 16 values -> shared m for its 4 rows
      float pm = fmaxf(fmaxf(st[0][0], st[0][1]), fmaxf(st[0][2], st[0][3]));
#pragma unroll
      for (int kt = 1; kt < 4; kt++) {
        pm = fmaxf(pm, fmaxf(fmaxf(st[kt][0], st[kt][1]), fmaxf(st[kt][2], st[kt][3])));
      }
      pm = fmaxf(pm, __shfl_xor(pm, 1, 64));
      pm = fmaxf(pm, __shfl_xor(pm, 2, 64));
      pm = fmaxf(pm, __shfl_xor(pm, 4, 64));
      pm = fmaxf(pm, __shfl_xor(pm, 8, 64));

      const bool grow = pm > m_g + 8.f;      // defer-max: P bounded by 2^8
      if (__any(grow)) {
        const float mnew = fmaxf(m_g, pm);
        const float al = exp2f(m_g - mnew);
        m_g = mnew;
#pragma unroll
        for (int nt = 0; nt < 4; nt++)
#pragma unroll
          for (int j = 0; j < 4; j++) o_[nt][j] *= al;
#pragma unroll
        for (int j = 0; j < 4; j++) l_[j] *= al;
      }

      float rs[4] = {0.f, 0.f, 0.f, 0.f};
#pragma unroll
      for (int kt = 0; kt < 4; kt++) {
#pragma unroll
        for (int j = 0; j < 4; j++) {
          const float p = exp2f(st[kt][j] - m_g);
          rs[j] += p;
          Ps[wid][lg * 4 + j][kt * 16 + l15] = f2bf_fast(p);
        }
      }
#pragma unroll
      for (int j = 0; j < 4; j++) {
        float s = rs[j];
        s += __shfl_xor(s, 1, 64);
        s += __shfl_xor(s, 2, 64);
        s += __shfl_xor(s, 4, 64);
        s += __shfl_xor(s, 8, 64);
        l_[j] += s;
      }

      // O += P V (P read back in A-frag layout)
#pragma unroll
      for (int c = 0; c < 2; c++) {
        const bf16x8 pa = *(const bf16x8*)(&Ps[wid][l15][c * 32 + lg * 8]);
#pragma unroll
        for (int nt = 0; nt < 4; nt++) {
          const bf16x8 vf = *(const bf16x8*)(&Vs[cur][nt * 16 + l15][c * 32 + lg * 8]);
          o_[nt] = __builtin_amdgcn_mfma_f32_16x16x32_bf16(pa, vf, o_[nt], 0, 0, 0);
        }
      }
    }

    if (pf) {   // write prefetched tile into the other buffer (vmcnt wait here)
      *(uint4*)(&Ks[cur ^ 1][srow][sc]) = kr;
      *(uint4*)(&Vs[cur ^ 1][srow][sc]) = vr;
    }
    cur ^= 1;
  }

  // epilogue: normalize and store bf16
  const long orow = (long)(b * TSEQ) + qw0;
#pragma unroll
  for (int j = 0; j < 4; j++) {
    const float inv = 1.f / l_[j];
#pragma unroll
    for (int nt = 0; nt < 4; nt++)
      o[(orow + lg * 4 + j) * DIM + h * 64 + nt * 16 + l15] = f2bf_fast(o_[nt][j] * inv);
  }
}

// ---------------- launch ----------------
extern "C" void kernel_launch(void* const* d_in, const int* in_sizes, int n_in,
                              void* d_out, int out_size, void* d_ws, size_t ws_size,
                              hipStream_t stream) {
  const float* x  = (const float*)d_in[0];
  const float* wq = (const float*)d_in[1];
  const float* wk = (const float*)d_in[2];
  const float* wv = (const float*)d_in[3];
  const float* wo = (const float*)d_in[4];
  float* out = (float*)d_out;

  ushort_t* ws = (ushort_t*)d_ws;
  const long NXB = (long)MROWS * DIM;               // 8388608
  ushort_t* xb   = ws;
  ushort_t* wtq  = xb  + NXB;                       // [2560][2048]
  ushort_t* woT  = wtq + (long)NQKV * DIM;          // [2048][2048]
  ushort_t* qws  = woT + (long)DIM * DIM;           // [4096][2048]
  ushort_t* kws  = qws + NXB;                       // [B,Hkv,T,D]
  ushort_t* vtws = kws + (long)BATCH * NKV * TSEQ * HD;  // [B,Hkv,D,T]
  ushort_t* aws  = vtws + (long)BATCH * NKV * TSEQ * HD; // [4096][2048]

  cast_bf16_k<<<(int)(NXB / 1024), 256, 0, stream>>>(x, xb, (int)(NXB / 4));
  transpose_cast<<<dim3(64, 64), 256, 0, stream>>>(wq, wtq, DIM, DIM);
  transpose_cast<<<dim3(64, 8),  256, 0, stream>>>(wk, wtq + (long)DIM  * DIM, DIM, 256);
  transpose_cast<<<dim3(64, 8),  256, 0, stream>>>(wv, wtq + (long)2304 * DIM, DIM, 256);
  transpose_cast<<<dim3(64, 64), 256, 0, stream>>>(wo, woT, DIM, DIM);

  gemm_bt<0><<<dim3(32, 20), 256, 0, stream>>>(xb, wtq, MROWS, NQKV, DIM,
                                               nullptr, qws, kws, vtws);
  rope_q_k<<<(MROWS * NH * 32) / 256, 256, 0, stream>>>(qws);
  rope_k_k<<<(BATCH * NKV * TSEQ * 32) / 256, 256, 0, stream>>>(kws);

  attn_mfma<<<BATCH * NH * (TSEQ / 128), 512, 0, stream>>>(qws, kws, vtws, aws);

  gemm_bt<1><<<dim3(32, 16), 256, 0, stream>>>(aws, woT, MROWS, DIM, DIM,
                                               out, nullptr, nullptr, nullptr);
}

// Round 6
// 236.980 us; speedup vs baseline: 17.2130x; 1.0703x over previous
//
#include <hip/hip_runtime.h>
#include <hip/hip_bf16.h>
#include <stdint.h>

#define DIM 2048
#define TSEQ 2048
#define BATCH 2
#define NH 32
#define NKV 4
#define HD 64
#define MROWS (BATCH*TSEQ)   // 4096
#define NQKV 2560            // 2048 q + 256 k + 256 v

typedef __attribute__((ext_vector_type(4))) float f32x4;
typedef __attribute__((ext_vector_type(8))) __bf16 bf16x8;
typedef unsigned short ushort_t;

// async global->LDS, 16B/lane: LDS dest = wave-uniform base + lane*16
#define GLDS16(g, l) __builtin_amdgcn_global_load_lds( \
    (const __attribute__((address_space(1))) void*)(g), \
    (__attribute__((address_space(3))) void*)(l), 16, 0, 0)

__device__ __forceinline__ float bflo2f(unsigned int w) {
  union { unsigned int i; float f; } c; c.i = w << 16; return c.f;
}
__device__ __forceinline__ unsigned short f2bf(float f) {
  union { float f; unsigned int i; } c; c.f = f;
  unsigned int x = c.i;
  x += 0x7fffu + ((x >> 16) & 1u);   // RTNE
  return (unsigned short)(x >> 16);
}
__device__ __forceinline__ unsigned short f2bf_fast(float f) {
  union { float f; unsigned int i; } c; c.f = f;
  return (unsigned short)((c.i + 0x8000u) >> 16);   // round-half-up
}

// ---------------- cast x (f32 -> bf16), 4 elems/thread ----------------
__global__ void cast_bf16_k(const float* __restrict__ in, ushort_t* __restrict__ out, int n4) {
  const int i = blockIdx.x * 256 + threadIdx.x;
  if (i >= n4) return;
  const float4 v = ((const float4*)in)[i];
  uint2 p;
  p.x = (unsigned int)f2bf(v.x) | ((unsigned int)f2bf(v.y) << 16);
  p.y = (unsigned int)f2bf(v.z) | ((unsigned int)f2bf(v.w) << 16);
  ((uint2*)out)[i] = p;
}

// ---------------- transpose-cast: w[K][N] f32 -> wt[N][K] bf16 ----------------
__global__ void transpose_cast(const float* __restrict__ w, ushort_t* __restrict__ wt, int K, int N) {
  __shared__ float tile[32][33];
  const int bk = blockIdx.x * 32;
  const int bn = blockIdx.y * 32;
  const int tx = threadIdx.x & 31;
  const int ty = threadIdx.x >> 5;  // 0..7
#pragma unroll
  for (int p = 0; p < 4; p++) {
    const int r = ty + p * 8;
    tile[r][tx] = w[(long)(bk + r) * N + bn + tx];
  }
  __syncthreads();
#pragma unroll
  for (int p = 0; p < 4; p++) {
    const int r = ty + p * 8;
    wt[(long)(bn + r) * K + bk + tx] = f2bf(tile[tx][r]);
  }
}

// ---------------- bf16 MFMA GEMM: C[M][N] = A[M][K] * BT[N][K]^T ----------------
// LDS staged via global_load_lds width=16 (m97 structure): linear [128][64] tiles.
template<int EPI>
__global__ __launch_bounds__(256, 2) void gemm_bt(
    const ushort_t* __restrict__ A, const ushort_t* __restrict__ BT,
    int M, int N, int K,
    float* __restrict__ Cf, ushort_t* __restrict__ Cq,
    ushort_t* __restrict__ Ck, ushort_t* __restrict__ Cv)
{
  __shared__ __align__(16) ushort_t As[128][64];
  __shared__ __align__(16) ushort_t Bs[128][64];
  const int tid  = threadIdx.x;
  const int lane = tid & 63;
  const int wid  = tid >> 6;
  const int wm   = wid >> 1, wn = wid & 1;   // 2x2 wave grid, 64x64 out each
  const int l8   = lane >> 3;                // 0..7: row within an 8-row chunk
  const int c8   = (lane & 7) * 8;           // ushort col within a 128B row
  const long abase = (long)blockIdx.x * 128 * K;
  const long bbase = (long)blockIdx.y * 128 * K;
  const int rsel = lane & 15;
  const int koff = (lane >> 4) * 8;
  f32x4 acc[4][4] = {};

  for (int k0 = 0; k0 < K; k0 += 64) {
    __syncthreads();   // previous-iter LDS reads complete
#pragma unroll
    for (int i = 0; i < 4; i++) {
      const int r0 = wid * 32 + i * 8;       // 8-row chunk staged per call
      GLDS16(&A [abase + (long)(r0 + l8) * K + k0 + c8], &As[r0][0]);
      GLDS16(&BT[bbase + (long)(r0 + l8) * K + k0 + c8], &Bs[r0][0]);
    }
    __syncthreads();   // vmcnt(0) drains the global_load_lds queue
#pragma unroll
    for (int kk = 0; kk < 64; kk += 32) {
      bf16x8 af[4], bfr[4];
#pragma unroll
      for (int m = 0; m < 4; m++) af[m]  = *(const bf16x8*)(&As[wm*64 + m*16 + rsel][kk + koff]);
#pragma unroll
      for (int n = 0; n < 4; n++) bfr[n] = *(const bf16x8*)(&Bs[wn*64 + n*16 + rsel][kk + koff]);
#pragma unroll
      for (int m = 0; m < 4; m++)
#pragma unroll
        for (int n = 0; n < 4; n++)
          acc[m][n] = __builtin_amdgcn_mfma_f32_16x16x32_bf16(af[m], bfr[n], acc[m][n], 0, 0, 0);
    }
  }

  const int rbase = blockIdx.x * 128 + wm * 64 + (lane >> 4) * 4;
  const int cbase = blockIdx.y * 128 + wn * 64 + (lane & 15);
#pragma unroll
  for (int m = 0; m < 4; m++) {
#pragma unroll
    for (int n = 0; n < 4; n++) {
      const int gn = cbase + n * 16;
#pragma unroll
      for (int j = 0; j < 4; j++) {
        const int gm = rbase + m * 16 + j;
        const float v = acc[m][n][j];
        if (EPI == 1) {
          Cf[(long)gm * N + gn] = v;
        } else {
          if (gn < DIM) {
            Cq[(long)gm * DIM + gn] = f2bf(v);
          } else {
            const int x = gn - DIM;
            const int hkv = (x >> 6) & 3;
            const int d = x & 63;
            const int b = gm >> 11;
            const int t = gm & (TSEQ - 1);
            if (x < 256) Ck[((long)(b * NKV + hkv) * TSEQ + t) * HD + d] = f2bf(v);
            else         Cv[((long)(b * NKV + hkv) * HD + d) * TSEQ + t] = f2bf(v);
          }
        }
      }
    }
  }
}

// ---------------- RoPE ----------------
// Q scale folds 1/sqrt(HD) * log2(e) = 0.125 * 1.4426950 (exp2-domain softmax).
#define LOG1E4_D32 0.2878231366242557f   // ln(10000)/32
#define QSCALE 0.1803368801111243f

__global__ void rope_q_k(ushort_t* __restrict__ q) {
  const int idx = blockIdx.x * 256 + threadIdx.x;  // MROWS*NH*32 threads
  const int m  = idx >> 10;
  const int rr = idx & 1023;
  const int h  = rr >> 5;
  const int d  = rr & 31;
  const int t  = m & (TSEQ - 1);
  const float ang = (float)t * __expf(-(float)d * LOG1E4_D32);
  float s_, c_;
  __sincosf(ang, &s_, &c_);
  const long base = (long)m * DIM + h * 64 + d;
  const float q0 = bflo2f(q[base]);
  const float q1 = bflo2f(q[base + 32]);
  q[base]      = f2bf((q0 * c_ - q1 * s_) * QSCALE);
  q[base + 32] = f2bf((q1 * c_ + q0 * s_) * QSCALE);
}

__global__ void rope_k_k(ushort_t* __restrict__ k) {
  const int idx = blockIdx.x * 256 + threadIdx.x;  // BATCH*NKV*TSEQ*32 threads
  const int row = idx >> 5;
  const int d   = idx & 31;
  const int t   = row & (TSEQ - 1);
  const float ang = (float)t * __expf(-(float)d * LOG1E4_D32);
  float s_, c_;
  __sincosf(ang, &s_, &c_);
  const long base = (long)row * HD + d;
  const float k0 = bflo2f(k[base]);
  const float k1 = bflo2f(k[base + 32]);
  k[base]      = f2bf(k0 * c_ - k1 * s_);
  k[base + 32] = f2bf(k1 * c_ + k0 * s_);
}

// ---------------- MFMA flash attention ----------------
// 8 waves, QBLK=128, KVBLK=64, single-buffer LDS (36.9KB -> 4 blocks/CU).
// Swapped QK^T: st = mfma(K, Q) -> C[key][q]; lane (lg,l15) holds 16 P-values
// for q=l15, keys kt*16+lg*4+j. Softmax per-q in col-form: in-lane tree +
// 2 shuffles. P packed to bf16 pairs via v_cvt_pk_bf16_f32 (adjacent j =
// adjacent keys), 8 b32 LDS writes. PV consumes Ps as A-frag (row=q).
__global__ __launch_bounds__(512, 4) void attn_mfma(
    const ushort_t* __restrict__ q, const ushort_t* __restrict__ k,
    const ushort_t* __restrict__ vt, ushort_t* __restrict__ o)
{
  __shared__ __align__(16) ushort_t Ks[64][72];       // [key][d]
  __shared__ __align__(16) ushort_t Vs[64][72];       // [d][key] (V^T)
  __shared__ __align__(16) ushort_t Ps[8][16][72];    // per-wave P [q][key]

  const int tid  = threadIdx.x;
  const int lane = tid & 63;
  const int wid  = tid >> 6;          // 0..7
  const int l15  = lane & 15;
  const int lg   = lane >> 4;         // 0..3

  const int bh  = blockIdx.x & 63;
  const int qt  = (TSEQ / 128 - 1) - (blockIdx.x >> 6);   // descending work
  const int h   = bh & (NH - 1);
  const int b   = bh >> 5;
  const int hkv = h >> 3;
  const int qbase = qt * 128;
  const int qw0   = qbase + wid * 16;

  // Q fragments (used as MFMA B-operand; same per-lane layout as A-frag).
  bf16x8 qf[2];
  {
    const ushort_t* qp = q + ((long)(b * TSEQ) + qw0 + l15) * DIM + h * 64 + lg * 8;
    qf[0] = *(const bf16x8*)(qp);
    qf[1] = *(const bf16x8*)(qp + 32);
  }

  const ushort_t* kb_ = k  + (long)(b * NKV + hkv) * TSEQ * HD;
  const ushort_t* vb_ = vt + (long)(b * NKV + hkv) * HD * TSEQ;

  float m_g = -1e30f;                 // running max for q = l15 (col-form)
  float l_c = 0.f;                    // running denom for q = l15
  f32x4 o_[4] = {};                   // O C-frag: row q = lg*4+j, col d = nt*16+l15

  const int srow = tid >> 3;          // 0..63
  const int sc   = (tid & 7) * 8;     // ushort offset, one uint4 per thread

  const int nkv = 2 * (qt + 1);

  // prologue: stage KV tile 0
  *(uint4*)(&Ks[srow][sc]) = *(const uint4*)(&kb_[(long)srow * HD + sc]);
  *(uint4*)(&Vs[srow][sc]) = *(const uint4*)(&vb_[(long)srow * TSEQ + sc]);
  __syncthreads();

  for (int kbv = 0; kbv < nkv; kbv++) {
    const int kb0 = kbv * 64;
    const bool pf = (kbv + 1 < nkv);
    uint4 kr = {}, vr = {};
    if (pf) {   // issue next-tile loads early; vmcnt waited at the ds_write below
      kr = *(const uint4*)(&kb_[(long)(kb0 + 64 + srow) * HD + sc]);
      vr = *(const uint4*)(&vb_[(long)srow * TSEQ + kb0 + 64 + sc]);
    }

    if (kb0 <= qw0 + 15) {             // wave-uniform: this wave has live keys
      // S^T = K Q^T: st[kt][j] = S[key = kb0+kt*16+lg*4+j][q = l15]
      f32x4 st[4] = {};
#pragma unroll
      for (int kt = 0; kt < 4; kt++) {
#pragma unroll
        for (int c = 0; c < 2; c++) {
          const bf16x8 kf = *(const bf16x8*)(&Ks[kt * 16 + l15][c * 32 + lg * 8]);
          st[kt] = __builtin_amdgcn_mfma_f32_16x16x32_bf16(kf, qf[c], st[kt], 0, 0, 0);
        }
      }

      if (kb0 + 63 > qw0) {            // diagonal block: causal mask
        const int qg = qw0 + l15;
#pragma unroll
        for (int kt = 0; kt < 4; kt++) {
          const int kg0 = kb0 + kt * 16 + lg * 4;
#pragma unroll
          for (int j = 0; j < 4; j++) {
            if (kg0 + j > qg) st[kt][j] = -1e30f;
          }
        }
      }

      // per-q max: in-lane tree over 16, then reduce across lg (xor 16, 32)
      float pm;
      {
        float mk0 = fmaxf(fmaxf(st[0][0], st[0][1]), fmaxf(st[0][2], st[0][3]));
        float mk1 = fmaxf(fmaxf(st[1][0], st[1][1]), fmaxf(st[1][2], st[1][3]));
        float mk2 = fmaxf(fmaxf(st[2][0], st[2][1]), fmaxf(st[2][2], st[2][3]));
        float mk3 = fmaxf(fmaxf(st[3][0], st[3][1]), fmaxf(st[3][2], st[3][3]));
        pm = fmaxf(fmaxf(mk0, mk1), fmaxf(mk2, mk3));
      }
      pm = fmaxf(pm, __shfl_xor(pm, 16, 64));
      pm = fmaxf(pm, __shfl_xor(pm, 32, 64));

      if (__any(pm > m_g + 8.f)) {     // defer-max: P bounded by 2^8
        const float mnew = fmaxf(m_g, pm);
        const float alc  = exp2f(m_g - mnew);   // col-form alpha (per q=l15)
        m_g = mnew;
        l_c *= alc;
        // O rows are q = lg*4+j: fetch row-form alpha from the lane holding that q
        float alr[4];
#pragma unroll
        for (int j = 0; j < 4; j++)
          alr[j] = __shfl(alc, (lane & 48) | (lg * 4 + j), 64);
#pragma unroll
        for (int nt = 0; nt < 4; nt++)
#pragma unroll
          for (int j = 0; j < 4; j++) o_[nt][j] *= alr[j];
      }

      // P = exp2(S - m), packed to bf16 pairs (adjacent j = adjacent keys)
      float rs = 0.f;
#pragma unroll
      for (int kt = 0; kt < 4; kt++) {
        const float p0 = exp2f(st[kt][0] - m_g);
        const float p1 = exp2f(st[kt][1] - m_g);
        const float p2 = exp2f(st[kt][2] - m_g);
        const float p3 = exp2f(st[kt][3] - m_g);
        rs += (p0 + p1) + (p2 + p3);
        unsigned int d0, d1;
        asm("v_cvt_pk_bf16_f32 %0, %1, %2" : "=v"(d0) : "v"(p0), "v"(p1));
        asm("v_cvt_pk_bf16_f32 %0, %1, %2" : "=v"(d1) : "v"(p2), "v"(p3));
        *(unsigned int*)(&Ps[wid][l15][kt * 16 + lg * 4])     = d0;
        *(unsigned int*)(&Ps[wid][l15][kt * 16 + lg * 4 + 2]) = d1;
      }
      rs += __shfl_xor(rs, 16, 64);
      rs += __shfl_xor(rs, 32, 64);
      l_c += rs;

      // O += P V (P as A-frag from Ps row q=l15; same-wave LDS round-trip)
#pragma unroll
      for (int c = 0; c < 2; c++) {
        const bf16x8 pa = *(const bf16x8*)(&Ps[wid][l15][c * 32 + lg * 8]);
#pragma unroll
        for (int nt = 0; nt < 4; nt++) {
          const bf16x8 vf = *(const bf16x8*)(&Vs[nt * 16 + l15][c * 32 + lg * 8]);
          o_[nt] = __builtin_amdgcn_mfma_f32_16x16x32_bf16(pa, vf, o_[nt], 0, 0, 0);
        }
      }
    }

    __syncthreads();                   // all reads of current tile done
    if (pf) {                          // write prefetched tile (vmcnt wait here)
      *(uint4*)(&Ks[srow][sc]) = kr;
      *(uint4*)(&Vs[srow][sc]) = vr;
    }
    __syncthreads();                   // new tile visible
  }

  // epilogue: normalize (row-form inv via col->row shuffle) and store bf16
  const long orow = (long)(b * TSEQ) + qw0;
#pragma unroll
  for (int j = 0; j < 4; j++) {
    const float inv = 1.f / __shfl(l_c, (lane & 48) | (lg * 4 + j), 64);
#pragma unroll
    for (int nt = 0; nt < 4; nt++)
      o[(orow + lg * 4 + j) * DIM + h * 64 + nt * 16 + l15] = f2bf_fast(o_[nt][j] * inv);
  }
}

// ---------------- launch ----------------
extern "C" void kernel_launch(void* const* d_in, const int* in_sizes, int n_in,
                              void* d_out, int out_size, void* d_ws, size_t ws_size,
                              hipStream_t stream) {
  const float* x  = (const float*)d_in[0];
  const float* wq = (const float*)d_in[1];
  const float* wk = (const float*)d_in[2];
  const float* wv = (const float*)d_in[3];
  const float* wo = (const float*)d_in[4];
  float* out = (float*)d_out;

  ushort_t* ws = (ushort_t*)d_ws;
  const long NXB = (long)MROWS * DIM;               // 8388608
  ushort_t* xb   = ws;
  ushort_t* wtq  = xb  + NXB;                       // [2560][2048]
  ushort_t* woT  = wtq + (long)NQKV * DIM;          // [2048][2048]
  ushort_t* qws  = woT + (long)DIM * DIM;           // [4096][2048]
  ushort_t* kws  = qws + NXB;                       // [B,Hkv,T,D]
  ushort_t* vtws = kws + (long)BATCH * NKV * TSEQ * HD;  // [B,Hkv,D,T]
  ushort_t* aws  = vtws + (long)BATCH * NKV * TSEQ * HD; // [4096][2048]

  cast_bf16_k<<<(int)(NXB / 1024), 256, 0, stream>>>(x, xb, (int)(NXB / 4));
  transpose_cast<<<dim3(64, 64), 256, 0, stream>>>(wq, wtq, DIM, DIM);
  transpose_cast<<<dim3(64, 8),  256, 0, stream>>>(wk, wtq + (long)DIM  * DIM, DIM, 256);
  transpose_cast<<<dim3(64, 8),  256, 0, stream>>>(wv, wtq + (long)2304 * DIM, DIM, 256);
  transpose_cast<<<dim3(64, 64), 256, 0, stream>>>(wo, woT, DIM, DIM);

  gemm_bt<0><<<dim3(32, 20), 256, 0, stream>>>(xb, wtq, MROWS, NQKV, DIM,
                                               nullptr, qws, kws, vtws);
  rope_q_k<<<(MROWS * NH * 32) / 256, 256, 0, stream>>>(qws);
  rope_k_k<<<(BATCH * NKV * TSEQ * 32) / 256, 256, 0, stream>>>(kws);

  attn_mfma<<<BATCH * NH * (TSEQ / 128), 512, 0, stream>>>(qws, kws, vtws, aws);

  gemm_bt<1><<<dim3(32, 16), 256, 0, stream>>>(aws, woT, MROWS, DIM, DIM,
                                               out, nullptr, nullptr, nullptr);
}

// Round 7
// 226.703 us; speedup vs baseline: 17.9933x; 1.0453x over previous
//
#include <hip/hip_runtime.h>
#include <hip/hip_bf16.h>
#include <stdint.h>

#define DIM 2048
#define TSEQ 2048
#define BATCH 2
#define NH 32
#define NKV 4
#define HD 64
#define MROWS (BATCH*TSEQ)   // 4096
#define NQKV 2560            // 2048 q + 256 k + 256 v

typedef __attribute__((ext_vector_type(4))) float f32x4;
typedef __attribute__((ext_vector_type(8))) __bf16 bf16x8;
typedef unsigned short ushort_t;

// async global->LDS, 16B/lane: LDS dest = wave-uniform base + lane*16
#define GLDS16(g, l) __builtin_amdgcn_global_load_lds( \
    (const __attribute__((address_space(1))) void*)(g), \
    (__attribute__((address_space(3))) void*)(l), 16, 0, 0)

__device__ __forceinline__ float bflo2f(unsigned int w) {
  union { unsigned int i; float f; } c; c.i = w << 16; return c.f;
}
__device__ __forceinline__ unsigned short f2bf(float f) {
  union { float f; unsigned int i; } c; c.f = f;
  unsigned int x = c.i;
  x += 0x7fffu + ((x >> 16) & 1u);   // RTNE
  return (unsigned short)(x >> 16);
}
__device__ __forceinline__ unsigned short f2bf_fast(float f) {
  union { float f; unsigned int i; } c; c.f = f;
  return (unsigned short)((c.i + 0x8000u) >> 16);   // round-half-up
}

// ---------------- cast x (f32 -> bf16), 4 elems/thread ----------------
__global__ void cast_bf16_k(const float* __restrict__ in, ushort_t* __restrict__ out, int n4) {
  const int i = blockIdx.x * 256 + threadIdx.x;
  if (i >= n4) return;
  const float4 v = ((const float4*)in)[i];
  uint2 p;
  p.x = (unsigned int)f2bf(v.x) | ((unsigned int)f2bf(v.y) << 16);
  p.y = (unsigned int)f2bf(v.z) | ((unsigned int)f2bf(v.w) << 16);
  ((uint2*)out)[i] = p;
}

// ---------------- transpose-cast: w[K][N] f32 -> wt[N][K] bf16 ----------------
__global__ void transpose_cast(const float* __restrict__ w, ushort_t* __restrict__ wt, int K, int N) {
  __shared__ float tile[32][33];
  const int bk = blockIdx.x * 32;
  const int bn = blockIdx.y * 32;
  const int tx = threadIdx.x & 31;
  const int ty = threadIdx.x >> 5;  // 0..7
#pragma unroll
  for (int p = 0; p < 4; p++) {
    const int r = ty + p * 8;
    tile[r][tx] = w[(long)(bk + r) * N + bn + tx];
  }
  __syncthreads();
#pragma unroll
  for (int p = 0; p < 4; p++) {
    const int r = ty + p * 8;
    wt[(long)(bn + r) * K + bk + tx] = f2bf(tile[tx][r]);
  }
}

// ---------------- bf16 MFMA GEMM: C[M][N] = A[M][K] * BT[N][K]^T ----------------
// LDS staged via global_load_lds width=16 (m97 structure): linear [128][64] tiles.
template<int EPI>
__global__ __launch_bounds__(256, 2) void gemm_bt(
    const ushort_t* __restrict__ A, const ushort_t* __restrict__ BT,
    int M, int N, int K,
    float* __restrict__ Cf, ushort_t* __restrict__ Cq,
    ushort_t* __restrict__ Ck, ushort_t* __restrict__ Cv)
{
  __shared__ __align__(16) ushort_t As[128][64];
  __shared__ __align__(16) ushort_t Bs[128][64];
  const int tid  = threadIdx.x;
  const int lane = tid & 63;
  const int wid  = tid >> 6;
  const int wm   = wid >> 1, wn = wid & 1;   // 2x2 wave grid, 64x64 out each
  const int l8   = lane >> 3;                // 0..7: row within an 8-row chunk
  const int c8   = (lane & 7) * 8;           // ushort col within a 128B row
  const long abase = (long)blockIdx.x * 128 * K;
  const long bbase = (long)blockIdx.y * 128 * K;
  const int rsel = lane & 15;
  const int koff = (lane >> 4) * 8;
  f32x4 acc[4][4] = {};

  for (int k0 = 0; k0 < K; k0 += 64) {
    __syncthreads();   // previous-iter LDS reads complete
#pragma unroll
    for (int i = 0; i < 4; i++) {
      const int r0 = wid * 32 + i * 8;       // 8-row chunk staged per call
      GLDS16(&A [abase + (long)(r0 + l8) * K + k0 + c8], &As[r0][0]);
      GLDS16(&BT[bbase + (long)(r0 + l8) * K + k0 + c8], &Bs[r0][0]);
    }
    __syncthreads();   // vmcnt(0) drains the global_load_lds queue
#pragma unroll
    for (int kk = 0; kk < 64; kk += 32) {
      bf16x8 af[4], bfr[4];
#pragma unroll
      for (int m = 0; m < 4; m++) af[m]  = *(const bf16x8*)(&As[wm*64 + m*16 + rsel][kk + koff]);
#pragma unroll
      for (int n = 0; n < 4; n++) bfr[n] = *(const bf16x8*)(&Bs[wn*64 + n*16 + rsel][kk + koff]);
#pragma unroll
      for (int m = 0; m < 4; m++)
#pragma unroll
        for (int n = 0; n < 4; n++)
          acc[m][n] = __builtin_amdgcn_mfma_f32_16x16x32_bf16(af[m], bfr[n], acc[m][n], 0, 0, 0);
    }
  }

  const int rbase = blockIdx.x * 128 + wm * 64 + (lane >> 4) * 4;
  const int cbase = blockIdx.y * 128 + wn * 64 + (lane & 15);
#pragma unroll
  for (int m = 0; m < 4; m++) {
#pragma unroll
    for (int n = 0; n < 4; n++) {
      const int gn = cbase + n * 16;
#pragma unroll
      for (int j = 0; j < 4; j++) {
        const int gm = rbase + m * 16 + j;
        const float v = acc[m][n][j];
        if (EPI == 1) {
          Cf[(long)gm * N + gn] = v;
        } else {
          if (gn < DIM) {
            Cq[(long)gm * DIM + gn] = f2bf(v);
          } else {
            const int x = gn - DIM;
            const int hkv = (x >> 6) & 3;
            const int d = x & 63;
            const int b = gm >> 11;
            const int t = gm & (TSEQ - 1);
            if (x < 256) Ck[((long)(b * NKV + hkv) * TSEQ + t) * HD + d] = f2bf(v);
            else         Cv[((long)(b * NKV + hkv) * HD + d) * TSEQ + t] = f2bf(v);
          }
        }
      }
    }
  }
}

// ---------------- RoPE ----------------
// Q scale folds 1/sqrt(HD) * log2(e) = 0.125 * 1.4426950 (exp2-domain softmax).
#define LOG1E4_D32 0.2878231366242557f   // ln(10000)/32
#define QSCALE 0.1803368801111243f

__global__ void rope_q_k(ushort_t* __restrict__ q) {
  const int idx = blockIdx.x * 256 + threadIdx.x;  // MROWS*NH*32 threads
  const int m  = idx >> 10;
  const int rr = idx & 1023;
  const int h  = rr >> 5;
  const int d  = rr & 31;
  const int t  = m & (TSEQ - 1);
  const float ang = (float)t * __expf(-(float)d * LOG1E4_D32);
  float s_, c_;
  __sincosf(ang, &s_, &c_);
  const long base = (long)m * DIM + h * 64 + d;
  const float q0 = bflo2f(q[base]);
  const float q1 = bflo2f(q[base + 32]);
  q[base]      = f2bf((q0 * c_ - q1 * s_) * QSCALE);
  q[base + 32] = f2bf((q1 * c_ + q0 * s_) * QSCALE);
}

__global__ void rope_k_k(ushort_t* __restrict__ k) {
  const int idx = blockIdx.x * 256 + threadIdx.x;  // BATCH*NKV*TSEQ*32 threads
  const int row = idx >> 5;
  const int d   = idx & 31;
  const int t   = row & (TSEQ - 1);
  const float ang = (float)t * __expf(-(float)d * LOG1E4_D32);
  float s_, c_;
  __sincosf(ang, &s_, &c_);
  const long base = (long)row * HD + d;
  const float k0 = bflo2f(k[base]);
  const float k1 = bflo2f(k[base + 32]);
  k[base]      = f2bf(k0 * c_ - k1 * s_);
  k[base + 32] = f2bf(k1 * c_ + k0 * s_);
}

// ---------------- MFMA flash attention ----------------
// 8 waves, QBLK=128, KVBLK=64. Double-buffered swizzled LDS (48KB -> 3 blk/CU),
// one raw lgkmcnt(0)+s_barrier per iter; prefetch loads in flight across it.
// All LDS tiles are linear 128B rows with 16B-granule XOR swizzle
// G' = G ^ (row&7), applied on write AND read (T2; conflict-free b128 reads).
// Swapped QK^T: st = mfma(K, Q) -> C[key][q]; softmax col-form per q=l15;
// P packed via v_cvt_pk_bf16_f32, consumed as PV A-frag through swizzled Ps.
__global__ __launch_bounds__(512, 6) void attn_mfma(
    const ushort_t* __restrict__ q, const ushort_t* __restrict__ k,
    const ushort_t* __restrict__ vt, ushort_t* __restrict__ o)
{
  __shared__ __align__(16) ushort_t Ks[2][64][64];    // [buf][key][d]   swz
  __shared__ __align__(16) ushort_t Vs[2][64][64];    // [buf][d][key]   swz
  __shared__ __align__(16) ushort_t Ps[8][16][64];    // per-wave P [q][key] swz

  const int tid  = threadIdx.x;
  const int lane = tid & 63;
  const int wid  = tid >> 6;          // 0..7
  const int l15  = lane & 15;
  const int lg   = lane >> 4;         // 0..3
  const int sw   = l15 & 7;           // read-side swizzle key (row&7 = l15&7)

  const int bh  = blockIdx.x & 63;
  const int qt  = (TSEQ / 128 - 1) - (blockIdx.x >> 6);   // descending work
  const int h   = bh & (NH - 1);
  const int b   = bh >> 5;
  const int hkv = h >> 3;
  const int qbase = qt * 128;
  const int qw0   = qbase + wid * 16;

  // Q fragments (used as MFMA B-operand; same per-lane layout as A-frag).
  bf16x8 qf[2];
  {
    const ushort_t* qp = q + ((long)(b * TSEQ) + qw0 + l15) * DIM + h * 64 + lg * 8;
    qf[0] = *(const bf16x8*)(qp);
    qf[1] = *(const bf16x8*)(qp + 32);
  }

  const ushort_t* kb_ = k  + (long)(b * NKV + hkv) * TSEQ * HD;
  const ushort_t* vb_ = vt + (long)(b * NKV + hkv) * HD * TSEQ;

  float m_g = -1e30f;                 // running max for q = l15 (col-form)
  float l_c = 0.f;                    // running denom for q = l15
  f32x4 o_[4] = {};                   // O C-frag: row q = lg*4+j, col d = nt*16+l15

  const int srow = tid >> 3;          // 0..63 staging row
  const int sgc  = (tid & 7) * 8;     // ushort col in global (linear)
  const int slc  = (((tid & 7) ^ (srow & 7))) * 8;  // swizzled LDS ushort col

  const int nkv = 2 * (qt + 1);

  // prologue: stage KV tile 0 into buf 0 (swizzled)
  *(uint4*)(&Ks[0][srow][slc]) = *(const uint4*)(&kb_[(long)srow * HD + sgc]);
  *(uint4*)(&Vs[0][srow][slc]) = *(const uint4*)(&vb_[(long)srow * TSEQ + sgc]);
  int cur = 0;

  for (int kbv = 0; kbv < nkv; kbv++) {
    const int kb0 = kbv * 64;
    const bool pf = (kbv + 1 < nkv);
    uint4 kr = {}, vr = {};
    if (pf) {   // issue next-tile loads early; vmcnt waited at the ds_write below
      kr = *(const uint4*)(&kb_[(long)(kb0 + 64 + srow) * HD + sgc]);
      vr = *(const uint4*)(&vb_[(long)srow * TSEQ + kb0 + 64 + sgc]);
    }
    // drain own LDS ops, then sync (no vmcnt drain -> prefetch stays in flight)
    asm volatile("s_waitcnt lgkmcnt(0)\n\ts_barrier" ::: "memory");

    if (kb0 <= qw0 + 15) {             // wave-uniform: this wave has live keys
      // S^T = K Q^T: st[kt][j] = S[key = kb0+kt*16+lg*4+j][q = l15]
      f32x4 st[4] = {};
#pragma unroll
      for (int kt = 0; kt < 4; kt++) {
#pragma unroll
        for (int c = 0; c < 2; c++) {
          const bf16x8 kf = *(const bf16x8*)(&Ks[cur][kt * 16 + l15][((4*c + lg) ^ sw) * 8]);
          st[kt] = __builtin_amdgcn_mfma_f32_16x16x32_bf16(kf, qf[c], st[kt], 0, 0, 0);
        }
      }

      if (kb0 + 63 > qw0) {            // diagonal block: causal mask
        const int qg = qw0 + l15;
#pragma unroll
        for (int kt = 0; kt < 4; kt++) {
          const int kg0 = kb0 + kt * 16 + lg * 4;
#pragma unroll
          for (int j = 0; j < 4; j++) {
            if (kg0 + j > qg) st[kt][j] = -1e30f;
          }
        }
      }

      // per-q max: in-lane tree over 16, then reduce across lg (xor 16, 32)
      float pm;
      {
        float mk0 = fmaxf(fmaxf(st[0][0], st[0][1]), fmaxf(st[0][2], st[0][3]));
        float mk1 = fmaxf(fmaxf(st[1][0], st[1][1]), fmaxf(st[1][2], st[1][3]));
        float mk2 = fmaxf(fmaxf(st[2][0], st[2][1]), fmaxf(st[2][2], st[2][3]));
        float mk3 = fmaxf(fmaxf(st[3][0], st[3][1]), fmaxf(st[3][2], st[3][3]));
        pm = fmaxf(fmaxf(mk0, mk1), fmaxf(mk2, mk3));
      }
      pm = fmaxf(pm, __shfl_xor(pm, 16, 64));
      pm = fmaxf(pm, __shfl_xor(pm, 32, 64));

      if (__any(pm > m_g + 8.f)) {     // defer-max: P bounded by 2^8
        const float mnew = fmaxf(m_g, pm);
        const float alc  = exp2f(m_g - mnew);   // col-form alpha (per q=l15)
        m_g = mnew;
        l_c *= alc;
        // O rows are q = lg*4+j: fetch row-form alpha from the lane holding that q
        float alr[4];
#pragma unroll
        for (int j = 0; j < 4; j++)
          alr[j] = __shfl(alc, (lane & 48) | (lg * 4 + j), 64);
#pragma unroll
        for (int nt = 0; nt < 4; nt++)
#pragma unroll
          for (int j = 0; j < 4; j++) o_[nt][j] *= alr[j];
      }

      // P = exp2(S - m), packed to bf16 pairs (adjacent j = adjacent keys)
      // write uint at row l15, byte col (32kt+8lg); granule G = 2kt+(lg>>1),
      // swizzled G' = G ^ sw, byte-in-granule 8*(lg&1)
      float rs = 0.f;
#pragma unroll
      for (int kt = 0; kt < 4; kt++) {
        const float p0 = exp2f(st[kt][0] - m_g);
        const float p1 = exp2f(st[kt][1] - m_g);
        const float p2 = exp2f(st[kt][2] - m_g);
        const float p3 = exp2f(st[kt][3] - m_g);
        rs += (p0 + p1) + (p2 + p3);
        unsigned int d0, d1;
        asm("v_cvt_pk_bf16_f32 %0, %1, %2" : "=v"(d0) : "v"(p0), "v"(p1));
        asm("v_cvt_pk_bf16_f32 %0, %1, %2" : "=v"(d1) : "v"(p2), "v"(p3));
        const int g0 = ((2 * kt + (lg >> 1)) ^ sw) * 8 + (lg & 1) * 4;
        *(unsigned int*)(&Ps[wid][l15][g0])     = d0;
        *(unsigned int*)(&Ps[wid][l15][g0 + 2]) = d1;
      }
      rs += __shfl_xor(rs, 16, 64);
      rs += __shfl_xor(rs, 32, 64);
      l_c += rs;

      // O += P V (P as A-frag from Ps row q=l15; same-wave LDS round-trip)
#pragma unroll
      for (int c = 0; c < 2; c++) {
        const bf16x8 pa = *(const bf16x8*)(&Ps[wid][l15][((4*c + lg) ^ sw) * 8]);
#pragma unroll
        for (int nt = 0; nt < 4; nt++) {
          const bf16x8 vf = *(const bf16x8*)(&Vs[cur][nt * 16 + l15][((4*c + lg) ^ sw) * 8]);
          o_[nt] = __builtin_amdgcn_mfma_f32_16x16x32_bf16(pa, vf, o_[nt], 0, 0, 0);
        }
      }
    }

    if (pf) {   // write prefetched tile into the other buffer (vmcnt wait here)
      *(uint4*)(&Ks[cur ^ 1][srow][slc]) = kr;
      *(uint4*)(&Vs[cur ^ 1][srow][slc]) = vr;
    }
    cur ^= 1;
  }

  // epilogue: normalize (row-form inv via col->row shuffle) and store bf16
  const long orow = (long)(b * TSEQ) + qw0;
#pragma unroll
  for (int j = 0; j < 4; j++) {
    const float inv = 1.f / __shfl(l_c, (lane & 48) | (lg * 4 + j), 64);
#pragma unroll
    for (int nt = 0; nt < 4; nt++)
      o[(orow + lg * 4 + j) * DIM + h * 64 + nt * 16 + l15] = f2bf_fast(o_[nt][j] * inv);
  }
}

// ---------------- launch ----------------
extern "C" void kernel_launch(void* const* d_in, const int* in_sizes, int n_in,
                              void* d_out, int out_size, void* d_ws, size_t ws_size,
                              hipStream_t stream) {
  const float* x  = (const float*)d_in[0];
  const float* wq = (const float*)d_in[1];
  const float* wk = (const float*)d_in[2];
  const float* wv = (const float*)d_in[3];
  const float* wo = (const float*)d_in[4];
  float* out = (float*)d_out;

  ushort_t* ws = (ushort_t*)d_ws;
  const long NXB = (long)MROWS * DIM;               // 8388608
  ushort_t* xb   = ws;
  ushort_t* wtq  = xb  + NXB;                       // [2560][2048]
  ushort_t* woT  = wtq + (long)NQKV * DIM;          // [2048][2048]
  ushort_t* qws  = woT + (long)DIM * DIM;           // [4096][2048]
  ushort_t* kws  = qws + NXB;                       // [B,Hkv,T,D]
  ushort_t* vtws = kws + (long)BATCH * NKV * TSEQ * HD;  // [B,Hkv,D,T]
  ushort_t* aws  = vtws + (long)BATCH * NKV * TSEQ * HD; // [4096][2048]

  cast_bf16_k<<<(int)(NXB / 1024), 256, 0, stream>>>(x, xb, (int)(NXB / 4));
  transpose_cast<<<dim3(64, 64), 256, 0, stream>>>(wq, wtq, DIM, DIM);
  transpose_cast<<<dim3(64, 8),  256, 0, stream>>>(wk, wtq + (long)DIM  * DIM, DIM, 256);
  transpose_cast<<<dim3(64, 8),  256, 0, stream>>>(wv, wtq + (long)2304 * DIM, DIM, 256);
  transpose_cast<<<dim3(64, 64), 256, 0, stream>>>(wo, woT, DIM, DIM);

  gemm_bt<0><<<dim3(32, 20), 256, 0, stream>>>(xb, wtq, MROWS, NQKV, DIM,
                                               nullptr, qws, kws, vtws);
  rope_q_k<<<(MROWS * NH * 32) / 256, 256, 0, stream>>>(qws);
  rope_k_k<<<(BATCH * NKV * TSEQ * 32) / 256, 256, 0, stream>>>(kws);

  attn_mfma<<<BATCH * NH * (TSEQ / 128), 512, 0, stream>>>(qws, kws, vtws, aws);

  gemm_bt<1><<<dim3(32, 16), 256, 0, stream>>>(aws, woT, MROWS, DIM, DIM,
                                               out, nullptr, nullptr, nullptr);
}